// Round 1
// baseline (3104.047 us; speedup 1.0000x reference)
//
#include <hip/hip_runtime.h>
#include <hip/hip_bf16.h>
#include <math.h>

// Problem constants
#define NB      16
#define LL      1024
#define EE      512
#define NHEADS  8
#define HDIM    64
#define DFF     2048
#define NLEVELS 10
#define NSCALES 11
#define BROWS   (NB * LL)       // 16384

// Workspace layout (floats). Total = 58,695,680 floats = ~224 MiB.
//  lvl : pyramid levels 1..10, channels-first, concatenated   (16*512*1023)
//  KV  : per-scale [K|V] rows: scale0 16384 rows, scale s: 16*(1024>>s) rows, 1024 cols
//  Q   : (16384, 512)  -- overwritten in-place by attention output
//  X   : (16384, 512)  -- src2 -> LN1(x)
//  FFH : (16384, 2048) at offset 0, overlaps lvl+KV (dead by FFN time)
static const size_t OFF_LVL = 0;
static const size_t SZ_LVL  = (size_t)16 * 512 * 1023;          // 8,380,416
static const size_t OFF_KV  = OFF_LVL + SZ_LVL;
static const size_t SZ_KV   = (size_t)32752 * 1024;             // 33,538,048
static const size_t OFF_Q   = OFF_KV + SZ_KV;                   // 41,918,464
static const size_t OFF_X   = OFF_Q + (size_t)BROWS * EE;       // 50,307,072

// ---------------------------------------------------------------------------
// Conv pyramid: one level per launch.
// out[n, h*64+o, t] = relu( sum_{ci,k} in[n, h*64+ci, 2t+k] * w[o,ci,k] + b[o] )
// src_layout=1: input is src (N, L, E); else channels-first (N, E, L_in).
// ---------------------------------------------------------------------------
__global__ void conv_level_kernel(const float* __restrict__ in,
                                  float* __restrict__ out,
                                  const float* __restrict__ w,   // (64,64,2)
                                  const float* __restrict__ bias, // (64)
                                  int L_in, int src_layout)
{
    const int L_out = L_in >> 1;
    __shared__ float wl[64 * 128];   // [ci][k][o] -> ci*128 + k*64 + o
    __shared__ float il[64 * 65];    // [ci][p], pitch 65 (bank-conflict pad)
    const int tid  = threadIdx.x;    // 256
    const int bp   = blockIdx.x;     // 0..127 (N*NHEADS)
    const int tblk = blockIdx.y;
    const int n = bp >> 3, h = bp & 7;

    // weights: global (o,ci,k) -> lds [ci*128 + k*64 + o]
    for (int idx = tid; idx < 8192; idx += 256) {
        int o = idx >> 7, ci = (idx >> 1) & 63, k = idx & 1;
        wl[ci * 128 + k * 64 + o] = w[idx];
    }
    const int t0 = tblk * 32;
    const int p0 = t0 * 2;
    if (src_layout) {
        // src (N, L, E): contiguous over ci
        int ci = tid & 63;
        for (int pp = tid >> 6; pp < 64; pp += 4) {
            int pg = p0 + pp;
            float v = (pg < L_in) ? in[(size_t)n * LL * EE + (size_t)pg * EE + h * 64 + ci] : 0.f;
            il[ci * 65 + pp] = v;
        }
    } else {
        // ch-first (N, E, L_in): contiguous over p
        int pp = tid & 63;
        int pg = p0 + pp;
        for (int ci = tid >> 6; ci < 64; ci += 4) {
            float v = (pg < L_in) ? in[(size_t)n * EE * L_in + (size_t)(h * 64 + ci) * L_in + pg] : 0.f;
            il[ci * 65 + pp] = v;
        }
    }
    __syncthreads();

    const int tl = tid & 31;
    const int t  = t0 + tl;
    if (t < L_out) {
        for (int o = tid >> 5; o < 64; o += 8) {
            float acc = bias[o];
            #pragma unroll 8
            for (int ci = 0; ci < 64; ci++) {
                acc += il[ci * 65 + 2 * tl]     * wl[ci * 128 + o];
                acc += il[ci * 65 + 2 * tl + 1] * wl[ci * 128 + 64 + o];
            }
            acc = fmaxf(acc, 0.f);
            out[(size_t)n * EE * L_out + (size_t)(h * 64 + o) * L_out + t] = acc;
        }
    }
}

// ---------------------------------------------------------------------------
// Generic fp32 tiled GEMM: C[M,Nout] = A[M,K] @ W[Nout,K]^T + bias (+res)(+relu)
// amode 0: A row-major (lda=K). amode 1: pyramid level, element (r,k) at
//          ((r>>log2Ls)*512 + k) << log2Ls) + (r & (Ls-1)).
// Nout must be a multiple of 64; K a multiple of 16.
// ---------------------------------------------------------------------------
__global__ void gemm_kernel(const float* __restrict__ A,
                            const float* __restrict__ W,
                            const float* __restrict__ bias,
                            const float* __restrict__ residual,
                            float* __restrict__ C,
                            int M, int K, int Nout,
                            int amode, int log2Ls, int relu)
{
    __shared__ float As[16][65];
    __shared__ float Bs[16][65];
    const int tid = threadIdx.x;          // 256
    const int tx = tid & 15, ty = tid >> 4;
    const int rowBase = blockIdx.y * 64;
    const int colBase = blockIdx.x * 64;
    float acc[4][4] = {};
    const int lr = tid >> 2;              // 0..63
    const int lk = (tid & 3) * 4;         // 0,4,8,12

    for (int kt = 0; kt < K; kt += 16) {
        {   // A tile
            int r = rowBase + lr;
            if (amode == 0) {
                float4 v = {0.f, 0.f, 0.f, 0.f};
                if (r < M) v = *(const float4*)&A[(size_t)r * K + kt + lk];
                As[lk + 0][lr] = v.x; As[lk + 1][lr] = v.y;
                As[lk + 2][lr] = v.z; As[lk + 3][lr] = v.w;
            } else {
                int nn = r >> log2Ls;
                int t  = r & ((1 << log2Ls) - 1);
                size_t base = (((size_t)nn * EE) << log2Ls) + t;
                #pragma unroll
                for (int j = 0; j < 4; j++) {
                    float v = 0.f;
                    if (r < M) v = A[base + ((size_t)(kt + lk + j) << log2Ls)];
                    As[lk + j][lr] = v;
                }
            }
        }
        {   // W tile
            int o = colBase + lr;
            float4 v = {0.f, 0.f, 0.f, 0.f};
            if (o < Nout) v = *(const float4*)&W[(size_t)o * K + kt + lk];
            Bs[lk + 0][lr] = v.x; Bs[lk + 1][lr] = v.y;
            Bs[lk + 2][lr] = v.z; Bs[lk + 3][lr] = v.w;
        }
        __syncthreads();
        #pragma unroll
        for (int k = 0; k < 16; k++) {
            float a[4], b[4];
            #pragma unroll
            for (int i = 0; i < 4; i++) a[i] = As[k][ty * 4 + i];
            #pragma unroll
            for (int i = 0; i < 4; i++) b[i] = Bs[k][tx * 4 + i];
            #pragma unroll
            for (int i = 0; i < 4; i++)
                #pragma unroll
                for (int j = 0; j < 4; j++) acc[i][j] += a[i] * b[j];
        }
        __syncthreads();
    }

    #pragma unroll
    for (int i = 0; i < 4; i++) {
        int r = rowBase + ty * 4 + i;
        if (r >= M) continue;
        int c = colBase + tx * 4;
        float4 v;
        float* pv = &v.x;
        #pragma unroll
        for (int j = 0; j < 4; j++) {
            float x = acc[i][j] + bias[c + j];
            if (residual) x += residual[(size_t)r * Nout + c + j];
            if (relu) x = fmaxf(x, 0.f);
            pv[j] = x;
        }
        *(float4*)&C[(size_t)r * Nout + c] = v;
    }
}

// ---------------------------------------------------------------------------
// Attention: one wave per row b. 8 lanes per head, 8 dims per lane.
// Scores over 11 scales -> softmax -> weighted V sum. Output overwrites Q row.
// ---------------------------------------------------------------------------
__device__ __forceinline__ int kv_row(int s, int b, int n, int l) {
    if (s == 0) return b;
    return 16384 + 16 * (1024 - (1024 >> (s - 1))) + n * (1024 >> s) + (l >> s);
}

__global__ void attn_kernel(const float* __restrict__ KV, float* __restrict__ QO)
{
    const int wv   = threadIdx.x >> 6;
    const int lane = threadIdx.x & 63;
    const int b    = blockIdx.x * 4 + wv;
    const int h    = lane >> 3;
    const int d8   = lane & 7;
    const int n = b >> 10, l = b & 1023;

    float q[8];
    const float* qp = &QO[(size_t)b * EE + h * 64 + d8 * 8];
    #pragma unroll
    for (int j = 0; j < 8; j++) q[j] = qp[j];

    float sc[NSCALES];
    #pragma unroll
    for (int s = 0; s < NSCALES; s++) {
        int row = kv_row(s, b, n, l);
        const float* kp = &KV[(size_t)row * 1024 + h * 64 + d8 * 8];
        float p = 0.f;
        #pragma unroll
        for (int j = 0; j < 8; j++) p += q[j] * kp[j];
        p += __shfl_xor(p, 1);
        p += __shfl_xor(p, 2);
        p += __shfl_xor(p, 4);
        sc[s] = p * 0.125f;   // 1/sqrt(64)
    }
    float m = sc[0];
    #pragma unroll
    for (int s = 1; s < NSCALES; s++) m = fmaxf(m, sc[s]);
    float sum = 0.f;
    #pragma unroll
    for (int s = 0; s < NSCALES; s++) { sc[s] = __expf(sc[s] - m); sum += sc[s]; }
    float inv = 1.f / sum;

    float o[8] = {};
    #pragma unroll
    for (int s = 0; s < NSCALES; s++) {
        int row = kv_row(s, b, n, l);
        const float* vp = &KV[(size_t)row * 1024 + 512 + h * 64 + d8 * 8];
        float a = sc[s] * inv;
        #pragma unroll
        for (int j = 0; j < 8; j++) o[j] += a * vp[j];
    }
    float* op = &QO[(size_t)b * EE + h * 64 + d8 * 8];
    #pragma unroll
    for (int j = 0; j < 8; j++) op[j] = o[j];
}

// ---------------------------------------------------------------------------
// LayerNorm over E=512, one block (256 threads) per row; in-place safe.
// ---------------------------------------------------------------------------
__global__ void ln_kernel(const float* __restrict__ in, float* __restrict__ out,
                          const float* __restrict__ w, const float* __restrict__ b)
{
    const int row = blockIdx.x;
    const int tid = threadIdx.x;
    float2 v = *(const float2*)&in[(size_t)row * EE + tid * 2];
    float s  = v.x + v.y;
    float s2 = v.x * v.x + v.y * v.y;
    #pragma unroll
    for (int m = 1; m < 64; m <<= 1) { s += __shfl_xor(s, m); s2 += __shfl_xor(s2, m); }
    __shared__ float ss[4], ss2[4];
    int wv = tid >> 6;
    if ((tid & 63) == 0) { ss[wv] = s; ss2[wv] = s2; }
    __syncthreads();
    s  = ss[0] + ss[1] + ss[2] + ss[3];
    s2 = ss2[0] + ss2[1] + ss2[2] + ss2[3];
    float mu  = s * (1.f / 512.f);
    float var = s2 * (1.f / 512.f) - mu * mu;
    float rs  = rsqrtf(var + 1e-5f);
    float2 o;
    o.x = (v.x - mu) * rs * w[tid * 2]     + b[tid * 2];
    o.y = (v.y - mu) * rs * w[tid * 2 + 1] + b[tid * 2 + 1];
    *(float2*)&out[(size_t)row * EE + tid * 2] = o;
}

// ---------------------------------------------------------------------------
extern "C" void kernel_launch(void* const* d_in, const int* in_sizes, int n_in,
                              void* d_out, int out_size, void* d_ws, size_t ws_size,
                              hipStream_t stream)
{
    const float* src        = (const float*)d_in[0];
    const float* conv_w     = (const float*)d_in[1];
    const float* conv_b     = (const float*)d_in[2];
    const float* in_proj_w  = (const float*)d_in[3];
    const float* in_proj_b  = (const float*)d_in[4];
    const float* out_proj_w = (const float*)d_in[5];
    const float* out_proj_b = (const float*)d_in[6];
    const float* ln1_w      = (const float*)d_in[7];
    const float* ln1_b      = (const float*)d_in[8];
    const float* ln2_w      = (const float*)d_in[9];
    const float* ln2_b      = (const float*)d_in[10];
    const float* w1         = (const float*)d_in[11];
    const float* b1         = (const float*)d_in[12];
    const float* w2         = (const float*)d_in[13];
    const float* b2         = (const float*)d_in[14];

    float* ws  = (float*)d_ws;
    float* out = (float*)d_out;
    float* lvl = ws + OFF_LVL;
    float* KV  = ws + OFF_KV;
    float* Q   = ws + OFF_Q;
    float* X   = ws + OFF_X;
    float* FFH = ws;   // overlaps lvl+KV (both dead by FFN time)

    // 1) conv pyramid (levels 1..10)
    {
        int L_in = LL;
        const float* inp = src;
        size_t off = 0;
        for (int i = 0; i < NLEVELS; i++) {
            int L_out = L_in >> 1;
            float* outp = lvl + off;
            dim3 g(NB * NHEADS, (L_out + 31) / 32);
            conv_level_kernel<<<g, 256, 0, stream>>>(
                inp, outp, conv_w + (size_t)i * 8192, conv_b + (size_t)i * 64,
                L_in, i == 0 ? 1 : 0);
            inp = outp;
            off += (size_t)NB * EE * L_out;
            L_in = L_out;
        }
    }

    // 2) Q projection: src @ Wq^T + bq
    gemm_kernel<<<dim3(EE / 64, BROWS / 64), 256, 0, stream>>>(
        src, in_proj_w, in_proj_b, nullptr, Q, BROWS, EE, EE, 0, 0, 0);

    // 3) KV scale 0: src @ [Wk;Wv]^T
    gemm_kernel<<<dim3(1024 / 64, BROWS / 64), 256, 0, stream>>>(
        src, in_proj_w + (size_t)EE * EE, in_proj_b + EE, nullptr, KV,
        BROWS, EE, 1024, 0, 0, 0);

    // 4) KV scales 1..10 from pyramid levels (strided A)
    {
        size_t off = 0;
        size_t rowoff = BROWS;
        for (int s = 1; s <= NLEVELS; s++) {
            int Ls = LL >> s;
            int M  = NB * Ls;
            gemm_kernel<<<dim3(1024 / 64, (M + 63) / 64), 256, 0, stream>>>(
                lvl + off, in_proj_w + (size_t)EE * EE, in_proj_b + EE, nullptr,
                KV + rowoff * 1024, M, EE, 1024, 1, 10 - s, 0);
            off += (size_t)NB * EE * Ls;
            rowoff += M;
        }
    }

    // 5) attention (writes o over Q in place)
    attn_kernel<<<BROWS / 4, 256, 0, stream>>>(KV, Q);

    // 6) out_proj -> X (= src2)
    gemm_kernel<<<dim3(EE / 64, BROWS / 64), 256, 0, stream>>>(
        Q, out_proj_w, out_proj_b, nullptr, X, BROWS, EE, EE, 0, 0, 0);

    // 7) LN1 in place: x = LN(src2)
    ln_kernel<<<BROWS, 256, 0, stream>>>(X, X, ln1_w, ln1_b);

    // 8) FFN1: relu(x @ w1^T + b1) -> FFH
    gemm_kernel<<<dim3(DFF / 64, BROWS / 64), 256, 0, stream>>>(
        X, w1, b1, nullptr, FFH, BROWS, EE, DFF, 0, 0, 1);

    // 9) FFN2 + residual: FFH @ w2^T + b2 + x -> out
    gemm_kernel<<<dim3(EE / 64, BROWS / 64), 256, 0, stream>>>(
        FFH, w2, b2, X, out, BROWS, DFF, EE, 0, 0, 0);

    // 10) LN2 in place on out
    ln_kernel<<<BROWS, 256, 0, stream>>>(out, out, ln2_w, ln2_b);
}

// Round 2
// 649.935 us; speedup vs baseline: 4.7759x; 4.7759x over previous
//
#include <hip/hip_runtime.h>
#include <hip/hip_bf16.h>
#include <stdint.h>
#include <math.h>

// Problem constants
#define NB      16
#define LL      1024
#define EE      512
#define NHEADS  8
#define DFF     2048
#define NLEVELS 10
#define NSCALES 11
#define BROWS   (NB * LL)       // 16384

typedef unsigned short u16;
typedef __attribute__((ext_vector_type(8))) short bf16x8;   // 8 bf16 = 4 VGPRs (MFMA A/B frag)
typedef __attribute__((ext_vector_type(4))) float f32x4;    // MFMA C/D frag

// ---------------- workspace layout (byte offsets) ----------------
// src_bf (16.78M) | lvl_f32 (33.52M) | lvl_bf (16.76M) | QKV (50.33M) |
// KVs (33.52M) | O_bf (16.78M) | X f32 (33.55M) | X_bf (16.78M) | wts (6.29M)
// FFH (67.11M) overlaps [0 .. 67.1M) — src_bf/lvl_f32/lvl_bf (+49KB of QKV), all dead by FFN time.
static const size_t B_SRCBF = 0;
static const size_t B_LVLF  = 16777216;
static const size_t B_LVLBF = 50298880;
static const size_t B_QKV   = 67059712;
static const size_t B_KVS   = 117391360;
static const size_t B_OBF   = 150913024;
static const size_t B_X     = 167690240;
static const size_t B_XBF   = 201244672;
static const size_t B_WBF   = 218021888;   // inw(786432) | outw(262144) | w1(1048576) | w2(1048576) elems
static const size_t B_FFH   = 0;

// ---------------- helpers ----------------
__device__ __forceinline__ u16 f2bf(float x) {
    union { float f; uint32_t u; } c; c.f = x;
    uint32_t u = c.u + 0x7FFFu + ((c.u >> 16) & 1u);
    return (u16)(u >> 16);
}
__device__ __forceinline__ float bf2f(u16 v) {
    union { uint32_t u; float f; } c; c.u = ((uint32_t)v) << 16; return c.f;
}
__device__ __forceinline__ void ld8bf(const u16* p, float* f) {
    uint4 r = *(const uint4*)p;
    uint32_t ws[4] = { r.x, r.y, r.z, r.w };
    #pragma unroll
    for (int j = 0; j < 4; j++) {
        union { uint32_t u; float g; } lo, hi;
        lo.u = ws[j] << 16; hi.u = ws[j] & 0xFFFF0000u;
        f[2 * j] = lo.g; f[2 * j + 1] = hi.g;
    }
}
__device__ __forceinline__ void gload16(const u16* g, u16* l) {
    // async global->LDS, 16B per lane; LDS dest = wave-uniform base + lane*16
    __builtin_amdgcn_global_load_lds(
        (const __attribute__((address_space(1))) void*)g,
        (__attribute__((address_space(3))) void*)l, 16, 0, 0);
}

// ---------------------------------------------------------------------------
// Fused cast kernel: src + 4 weight tensors -> bf16. Each thread: 4 elems.
// segments (thread counts/4): src 2097152, inw 196608, outw 65536, w1 262144, w2 262144
// blocks: 8192 | 768 | 256 | 1024 | 1024  -> total 11264
// ---------------------------------------------------------------------------
__global__ void cast_all_kernel(const float* __restrict__ s0, const float* __restrict__ s1,
                                const float* __restrict__ s2, const float* __restrict__ s3,
                                const float* __restrict__ s4,
                                u16* __restrict__ d0, u16* __restrict__ d1,
                                u16* __restrict__ d2, u16* __restrict__ d3,
                                u16* __restrict__ d4)
{
    int bid = blockIdx.x;
    const float* s; u16* d; int nt;
    if      (bid < 8192)  { s = s0; d = d0; nt = 2097152; }
    else if (bid < 8960)  { bid -= 8192;  s = s1; d = d1; nt = 196608; }
    else if (bid < 9216)  { bid -= 8960;  s = s2; d = d2; nt = 65536;  }
    else if (bid < 10240) { bid -= 9216;  s = s3; d = d3; nt = 262144; }
    else                  { bid -= 10240; s = s4; d = d4; nt = 262144; }
    int i = bid * 256 + threadIdx.x;
    if (i < nt) {
        float4 v = ((const float4*)s)[i];
        uint2 o;
        o.x = (uint32_t)f2bf(v.x) | ((uint32_t)f2bf(v.y) << 16);
        o.y = (uint32_t)f2bf(v.z) | ((uint32_t)f2bf(v.w) << 16);
        ((uint2*)d)[i] = o;
    }
}

// ---------------------------------------------------------------------------
// Conv pyramid level (fp32, unchanged from round 1)
// ---------------------------------------------------------------------------
__global__ void conv_level_kernel(const float* __restrict__ in,
                                  float* __restrict__ out,
                                  const float* __restrict__ w,
                                  const float* __restrict__ bias,
                                  int L_in, int src_layout)
{
    const int L_out = L_in >> 1;
    __shared__ float wl[64 * 128];
    __shared__ float il[64 * 65];
    const int tid  = threadIdx.x;
    const int bp   = blockIdx.x;
    const int tblk = blockIdx.y;
    const int n = bp >> 3, h = bp & 7;

    for (int idx = tid; idx < 8192; idx += 256) {
        int o = idx >> 7, ci = (idx >> 1) & 63, k = idx & 1;
        wl[ci * 128 + k * 64 + o] = w[idx];
    }
    const int t0 = tblk * 32;
    const int p0 = t0 * 2;
    if (src_layout) {
        int ci = tid & 63;
        for (int pp = tid >> 6; pp < 64; pp += 4) {
            int pg = p0 + pp;
            float v = (pg < L_in) ? in[(size_t)n * LL * EE + (size_t)pg * EE + h * 64 + ci] : 0.f;
            il[ci * 65 + pp] = v;
        }
    } else {
        int pp = tid & 63;
        int pg = p0 + pp;
        for (int ci = tid >> 6; ci < 64; ci += 4) {
            float v = (pg < L_in) ? in[(size_t)n * EE * L_in + (size_t)(h * 64 + ci) * L_in + pg] : 0.f;
            il[ci * 65 + pp] = v;
        }
    }
    __syncthreads();

    const int tl = tid & 31;
    const int t  = t0 + tl;
    if (t < L_out) {
        for (int o = tid >> 5; o < 64; o += 8) {
            float acc = bias[o];
            #pragma unroll 8
            for (int ci = 0; ci < 64; ci++) {
                acc += il[ci * 65 + 2 * tl]     * wl[ci * 128 + o];
                acc += il[ci * 65 + 2 * tl + 1] * wl[ci * 128 + 64 + o];
            }
            acc = fmaxf(acc, 0.f);
            out[(size_t)n * EE * L_out + (size_t)(h * 64 + o) * L_out + t] = acc;
        }
    }
}

// ---------------------------------------------------------------------------
// Transpose-cast all pyramid levels: (N,E,Ls) f32 ch-first -> (rows,512) bf16.
// One launch, 2688 blocks; level found by walking hardcoded block counts.
// ---------------------------------------------------------------------------
__global__ void transpose_levels_kernel(const float* __restrict__ lvlf, u16* __restrict__ lvlbf)
{
    __shared__ float tile[64][65];
    int bid = blockIdx.x;
    int Ls = 512; size_t offIn = 0; int rowOff = 0;
    while (true) {
        int TT = (Ls + 63) >> 6;
        int nb = 16 * TT * 8;
        if (bid < nb) break;
        bid -= nb; offIn += (size_t)16 * 512 * Ls; rowOff += 16 * Ls; Ls >>= 1;
    }
    int TT = (Ls + 63) >> 6;
    int et = bid & 7;
    int rest = bid >> 3;
    int tt = rest % TT;
    int n  = rest / TT;
    int t0 = tt * 64, e0 = et * 64;
    const int tid = threadIdx.x, tl = tid & 63;

    for (int er = tid >> 6; er < 64; er += 4) {
        int t = t0 + tl;
        tile[er][tl] = (t < Ls) ? lvlf[offIn + ((size_t)n * 512 + e0 + er) * Ls + t] : 0.f;
    }
    __syncthreads();
    for (int tr = tid >> 6; tr < 64; tr += 4) {
        int t = t0 + tr;
        if (t < Ls)
            lvlbf[((size_t)(rowOff + n * Ls + t)) * 512 + e0 + tl] = f2bf(tile[tl][tr]);
    }
}

// ---------------------------------------------------------------------------
// bf16 MFMA GEMM (m97 structure): C[M,N] = A[M,K] @ W[N,K]^T + bias (+res)(+relu)
// A,W bf16 row-major K-contiguous. Tile 128x128, BK=32, 256 thr = 4 waves (2x2),
// wave = 64x64 via 4x4 mfma_f32_16x16x32_bf16. global_load_lds width-16 staging.
// N % 128 == 0, K % 32 == 0. Staging rows clamped to M-1 (C-write guarded).
// ---------------------------------------------------------------------------
__global__ __launch_bounds__(256, 2)
void mfma_gemm(const u16* __restrict__ A, const u16* __restrict__ W,
               const float* __restrict__ bias, const float* __restrict__ residual,
               float* __restrict__ Cf, u16* __restrict__ Cb,
               int M, int K, int N, int relu)
{
    __shared__ u16 As[128 * 32];
    __shared__ u16 Bs[128 * 32];
    const int tid = threadIdx.x;
    const int l = tid & 63, w = tid >> 6;
    const int wm = w >> 1, wn = w & 1;
    const int rowBase = blockIdx.y * 128;
    const int colBase = blockIdx.x * 128;

    f32x4 acc[4][4];
    #pragma unroll
    for (int m = 0; m < 4; m++)
        #pragma unroll
        for (int n = 0; n < 4; n++) acc[m][n] = 0.f;

    int rA0 = rowBase + w * 16 + (l >> 2);        if (rA0 > M - 1) rA0 = M - 1;
    int rA1 = rowBase + 64 + w * 16 + (l >> 2);   if (rA1 > M - 1) rA1 = M - 1;
    const u16* gA0 = A + (size_t)rA0 * K + (l & 3) * 8;
    const u16* gA1 = A + (size_t)rA1 * K + (l & 3) * 8;
    const u16* gB0 = W + (size_t)(colBase + w * 16 + (l >> 2)) * K + (l & 3) * 8;
    const u16* gB1 = W + (size_t)(colBase + 64 + w * 16 + (l >> 2)) * K + (l & 3) * 8;
    u16* lA = As + w * 512;    // wave-uniform: wave w stages rows [w*16, w*16+16)
    u16* lB = Bs + w * 512;

    for (int kt = 0; kt < K; kt += 32) {
        gload16(gA0 + kt, lA);
        gload16(gA1 + kt, lA + 64 * 32);
        gload16(gB0 + kt, lB);
        gload16(gB1 + kt, lB + 64 * 32);
        __syncthreads();   // drains vmcnt before reads

        const u16* pa = As + (wm * 64 + (l & 15)) * 32 + (l >> 4) * 8;
        const u16* pb = Bs + (wn * 64 + (l & 15)) * 32 + (l >> 4) * 8;
        bf16x8 av[4], bv[4];
        #pragma unroll
        for (int m = 0; m < 4; m++) av[m] = *(const bf16x8*)(pa + m * 512);
        #pragma unroll
        for (int n = 0; n < 4; n++) bv[n] = *(const bf16x8*)(pb + n * 512);
        #pragma unroll
        for (int m = 0; m < 4; m++)
            #pragma unroll
            for (int n = 0; n < 4; n++)
                acc[m][n] = __builtin_amdgcn_mfma_f32_16x16x32_bf16(av[m], bv[n], acc[m][n], 0, 0, 0);
        __syncthreads();   // protect LDS from next-iter staging
    }

    // epilogue: D[row][col], col = lane&15 (+n*16), row = (lane>>4)*4+reg (+m*16)
    const int cc = colBase + wn * 64 + (l & 15);
    float bs4[4];
    #pragma unroll
    for (int n = 0; n < 4; n++) bs4[n] = bias[cc + n * 16];
    #pragma unroll
    for (int m = 0; m < 4; m++) {
        #pragma unroll
        for (int reg = 0; reg < 4; reg++) {
            int row = rowBase + wm * 64 + m * 16 + (l >> 4) * 4 + reg;
            if (row < M) {
                #pragma unroll
                for (int n = 0; n < 4; n++) {
                    int col = cc + n * 16;
                    float v = acc[m][n][reg] + bs4[n];
                    if (residual) v += residual[(size_t)row * N + col];
                    if (relu) v = fmaxf(v, 0.f);
                    if (Cb) Cb[(size_t)row * N + col] = f2bf(v);
                    else    Cf[(size_t)row * N + col] = v;
                }
            }
        }
    }
}

// ---------------------------------------------------------------------------
// Attention (bf16 in/out): one wave per row b; 8 lanes/head, 8 dims/lane.
// Q/K0/V0 from QKV (row b, cols 0/512/1024); scales 1..10 from KVs.
// ---------------------------------------------------------------------------
__global__ void attn_kernel(const u16* __restrict__ QKV, const u16* __restrict__ KVs,
                            u16* __restrict__ O)
{
    const int wv   = threadIdx.x >> 6;
    const int lane = threadIdx.x & 63;
    const int b    = blockIdx.x * 4 + wv;
    const int h    = lane >> 3;
    const int d8   = lane & 7;
    const int n = b >> 10, pos = b & 1023;

    float q[8];
    ld8bf(QKV + (size_t)b * 1536 + h * 64 + d8 * 8, q);

    float sc[NSCALES];
    {
        float kk[8];
        ld8bf(QKV + (size_t)b * 1536 + 512 + h * 64 + d8 * 8, kk);
        float p = 0.f;
        #pragma unroll
        for (int j = 0; j < 8; j++) p += q[j] * kk[j];
        p += __shfl_xor(p, 1); p += __shfl_xor(p, 2); p += __shfl_xor(p, 4);
        sc[0] = p * 0.125f;
    }
    {
        int rowOff = 0;
        #pragma unroll
        for (int s = 1; s <= NLEVELS; s++) {
            int Ls = 1024 >> s;
            int row = rowOff + n * Ls + (pos >> s);
            float kk[8];
            ld8bf(KVs + (size_t)row * 1024 + h * 64 + d8 * 8, kk);
            float p = 0.f;
            #pragma unroll
            for (int j = 0; j < 8; j++) p += q[j] * kk[j];
            p += __shfl_xor(p, 1); p += __shfl_xor(p, 2); p += __shfl_xor(p, 4);
            sc[s] = p * 0.125f;
            rowOff += 16 * Ls;
        }
    }
    float m = sc[0];
    #pragma unroll
    for (int s = 1; s < NSCALES; s++) m = fmaxf(m, sc[s]);
    float sum = 0.f;
    #pragma unroll
    for (int s = 0; s < NSCALES; s++) { sc[s] = __expf(sc[s] - m); sum += sc[s]; }
    float inv = 1.f / sum;

    float o[8] = {};
    {
        float vv[8];
        ld8bf(QKV + (size_t)b * 1536 + 1024 + h * 64 + d8 * 8, vv);
        float a = sc[0] * inv;
        #pragma unroll
        for (int j = 0; j < 8; j++) o[j] += a * vv[j];
    }
    {
        int rowOff = 0;
        #pragma unroll
        for (int s = 1; s <= NLEVELS; s++) {
            int Ls = 1024 >> s;
            int row = rowOff + n * Ls + (pos >> s);
            float vv[8];
            ld8bf(KVs + (size_t)row * 1024 + 512 + h * 64 + d8 * 8, vv);
            float a = sc[s] * inv;
            #pragma unroll
            for (int j = 0; j < 8; j++) o[j] += a * vv[j];
            rowOff += 16 * Ls;
        }
    }
    uint4 pk;
    pk.x = (uint32_t)f2bf(o[0]) | ((uint32_t)f2bf(o[1]) << 16);
    pk.y = (uint32_t)f2bf(o[2]) | ((uint32_t)f2bf(o[3]) << 16);
    pk.z = (uint32_t)f2bf(o[4]) | ((uint32_t)f2bf(o[5]) << 16);
    pk.w = (uint32_t)f2bf(o[6]) | ((uint32_t)f2bf(o[7]) << 16);
    *(uint4*)(O + (size_t)b * 512 + h * 64 + d8 * 8) = pk;
}

// ---------------------------------------------------------------------------
// LayerNorm over E=512; optional secondary bf16 output.
// ---------------------------------------------------------------------------
__global__ void ln_kernel(const float* __restrict__ in, float* __restrict__ out,
                          const float* __restrict__ w, const float* __restrict__ b,
                          u16* __restrict__ out_bf)
{
    const int row = blockIdx.x;
    const int tid = threadIdx.x;
    float2 v = *(const float2*)&in[(size_t)row * EE + tid * 2];
    float s  = v.x + v.y;
    float s2 = v.x * v.x + v.y * v.y;
    #pragma unroll
    for (int m = 1; m < 64; m <<= 1) { s += __shfl_xor(s, m); s2 += __shfl_xor(s2, m); }
    __shared__ float ss[4], ss2[4];
    int wv = tid >> 6;
    if ((tid & 63) == 0) { ss[wv] = s; ss2[wv] = s2; }
    __syncthreads();
    s  = ss[0] + ss[1] + ss[2] + ss[3];
    s2 = ss2[0] + ss2[1] + ss2[2] + ss2[3];
    float mu  = s * (1.f / 512.f);
    float var = s2 * (1.f / 512.f) - mu * mu;
    float rs  = rsqrtf(var + 1e-5f);
    float2 o;
    o.x = (v.x - mu) * rs * w[tid * 2]     + b[tid * 2];
    o.y = (v.y - mu) * rs * w[tid * 2 + 1] + b[tid * 2 + 1];
    *(float2*)&out[(size_t)row * EE + tid * 2] = o;
    if (out_bf) {
        uint32_t pk = (uint32_t)f2bf(o.x) | ((uint32_t)f2bf(o.y) << 16);
        *(uint32_t*)&out_bf[(size_t)row * EE + tid * 2] = pk;
    }
}

// ---------------------------------------------------------------------------
extern "C" void kernel_launch(void* const* d_in, const int* in_sizes, int n_in,
                              void* d_out, int out_size, void* d_ws, size_t ws_size,
                              hipStream_t stream)
{
    const float* src        = (const float*)d_in[0];
    const float* conv_w     = (const float*)d_in[1];
    const float* conv_b     = (const float*)d_in[2];
    const float* in_proj_w  = (const float*)d_in[3];
    const float* in_proj_b  = (const float*)d_in[4];
    const float* out_proj_w = (const float*)d_in[5];
    const float* out_proj_b = (const float*)d_in[6];
    const float* ln1_w      = (const float*)d_in[7];
    const float* ln1_b      = (const float*)d_in[8];
    const float* ln2_w      = (const float*)d_in[9];
    const float* ln2_b      = (const float*)d_in[10];
    const float* w1         = (const float*)d_in[11];
    const float* b1         = (const float*)d_in[12];
    const float* w2         = (const float*)d_in[13];
    const float* b2         = (const float*)d_in[14];

    char*  wsb    = (char*)d_ws;
    float* out    = (float*)d_out;
    u16*   src_bf = (u16*)(wsb + B_SRCBF);
    float* lvlf   = (float*)(wsb + B_LVLF);
    u16*   lvl_bf = (u16*)(wsb + B_LVLBF);
    u16*   QKV    = (u16*)(wsb + B_QKV);
    u16*   KVs    = (u16*)(wsb + B_KVS);
    u16*   O_bf   = (u16*)(wsb + B_OBF);
    float* X      = (float*)(wsb + B_X);
    u16*   X_bf   = (u16*)(wsb + B_XBF);
    u16*   inw_bf = (u16*)(wsb + B_WBF);
    u16*   outw_bf= inw_bf + 786432;
    u16*   w1_bf  = outw_bf + 262144;
    u16*   w2_bf  = w1_bf + 1048576;
    u16*   FFH    = (u16*)(wsb + B_FFH);

    // 0) cast src + weights to bf16
    cast_all_kernel<<<11264, 256, 0, stream>>>(src, in_proj_w, out_proj_w, w1, w2,
                                               src_bf, inw_bf, outw_bf, w1_bf, w2_bf);

    // 1) conv pyramid (fp32, 10 levels)
    {
        int L_in = LL;
        const float* inp = src;
        size_t off = 0;
        for (int i = 0; i < NLEVELS; i++) {
            int L_out = L_in >> 1;
            float* outp = lvlf + off;
            dim3 g(NB * NHEADS, (L_out + 31) / 32);
            conv_level_kernel<<<g, 256, 0, stream>>>(
                inp, outp, conv_w + (size_t)i * 8192, conv_b + (size_t)i * 64,
                L_in, i == 0 ? 1 : 0);
            inp = outp;
            off += (size_t)NB * EE * L_out;
            L_in = L_out;
        }
    }

    // 2) transpose+cast levels -> lvl_bf (16368 x 512)
    transpose_levels_kernel<<<2688, 256, 0, stream>>>(lvlf, lvl_bf);

    // 3) QKV = src_bf @ in_proj_w^T + b  (16384 x 1536)
    mfma_gemm<<<dim3(12, 128), 256, 0, stream>>>(
        src_bf, inw_bf, in_proj_b, nullptr, nullptr, QKV, BROWS, EE, 1536, 0);

    // 4) KVs = lvl_bf @ Wkv^T + b_kv  (16368 x 1024)
    mfma_gemm<<<dim3(8, 128), 256, 0, stream>>>(
        lvl_bf, inw_bf + (size_t)512 * 512, in_proj_b + 512, nullptr, nullptr, KVs,
        16368, EE, 1024, 0);

    // 5) attention -> O_bf
    attn_kernel<<<BROWS / 4, 256, 0, stream>>>(QKV, KVs, O_bf);

    // 6) X = O_bf @ out_proj^T + b  (fp32)
    mfma_gemm<<<dim3(4, 128), 256, 0, stream>>>(
        O_bf, outw_bf, out_proj_b, nullptr, X, nullptr, BROWS, EE, EE, 0);

    // 7) LN1 in place (+ bf16 copy)
    ln_kernel<<<BROWS, 256, 0, stream>>>(X, X, ln1_w, ln1_b, X_bf);

    // 8) FFH = relu(X_bf @ w1^T + b1)  (bf16)
    mfma_gemm<<<dim3(16, 128), 256, 0, stream>>>(
        X_bf, w1_bf, b1, nullptr, nullptr, FFH, BROWS, EE, DFF, 1);

    // 9) out = FFH @ w2^T + b2 + X  (fp32)
    mfma_gemm<<<dim3(4, 128), 256, 0, stream>>>(
        FFH, w2_bf, b2, X, out, nullptr, BROWS, DFF, EE, 0);

    // 10) LN2 in place on out
    ln_kernel<<<BROWS, 256, 0, stream>>>(out, out, ln2_w, ln2_b, nullptr);
}

// Round 3
// 373.191 us; speedup vs baseline: 8.3176x; 1.7416x over previous
//
#include <hip/hip_runtime.h>
#include <hip/hip_bf16.h>
#include <stdint.h>
#include <math.h>

// Problem constants
#define NB      16
#define LL      1024
#define EE      512
#define NHEADS  8
#define DFF     2048
#define NLEVELS 10
#define NSCALES 11
#define BROWS   (NB * LL)       // 16384

typedef unsigned short u16;
typedef __attribute__((ext_vector_type(8))) short bf16x8;   // 8 bf16 = 4 VGPRs (MFMA A/B frag)
typedef __attribute__((ext_vector_type(4))) float f32x4;    // MFMA C/D frag

// ---------------- workspace layout (byte offsets) ----------------
// src_bf 16.78M | lvl_bf 16.76M | QKV 50.33M | KVs 33.52M | O_bf 16.78M |
// X f32 33.55M | X_bf 16.78M | weights ~6.5M
// FFH (67.11MB @0) overlaps src_bf+lvl_bf+QKV[0:33.57M] — all dead by FFN1 time.
static const size_t B_SRCBF = 0;                         // 16,777,216
static const size_t B_LVLBF = 16777216;                  // 16,760,832
static const size_t B_QKV   = 33538048;                  // 50,331,648
static const size_t B_KVS   = 83869696;                  // 33,521,664
static const size_t B_OBF   = 117391360;                 // 16,777,216
static const size_t B_X     = 134168576;                 // 33,554,432
static const size_t B_XBF   = 167723008;                 // 16,777,216
static const size_t B_WBF   = 184500224;                 // weights
static const size_t B_FFH   = 0;

// ---------------- helpers ----------------
__device__ __forceinline__ u16 f2bf(float x) {
    union { float f; uint32_t u; } c; c.f = x;
    uint32_t u = c.u + 0x7FFFu + ((c.u >> 16) & 1u);
    return (u16)(u >> 16);
}
__device__ __forceinline__ void ld8bf(const u16* p, float* f) {
    uint4 r = *(const uint4*)p;
    uint32_t ws[4] = { r.x, r.y, r.z, r.w };
    #pragma unroll
    for (int j = 0; j < 4; j++) {
        union { uint32_t u; float g; } lo, hi;
        lo.u = ws[j] << 16; hi.u = ws[j] & 0xFFFF0000u;
        f[2 * j] = lo.g; f[2 * j + 1] = hi.g;
    }
}
__device__ __forceinline__ void gload16(const u16* g, u16* l) {
    __builtin_amdgcn_global_load_lds(
        (const __attribute__((address_space(1))) void*)g,
        (__attribute__((address_space(3))) void*)l, 16, 0, 0);
}

// ---------------------------------------------------------------------------
// Fused cast kernel: src + 4 weight tensors -> bf16, plus conv_w repack:
// wr[lvl][o][k*64+ci] = conv_w[lvl][o][ci][k].
// blocks: src 8192 | inw 768 | outw 256 | w1 1024 | w2 1024 | convw 80 = 11344
// ---------------------------------------------------------------------------
__global__ void cast_all_kernel(const float* __restrict__ s0, const float* __restrict__ s1,
                                const float* __restrict__ s2, const float* __restrict__ s3,
                                const float* __restrict__ s4, const float* __restrict__ cw,
                                u16* __restrict__ d0, u16* __restrict__ d1,
                                u16* __restrict__ d2, u16* __restrict__ d3,
                                u16* __restrict__ d4, u16* __restrict__ dw)
{
    int bid = blockIdx.x;
    if (bid >= 11264) {   // conv_w repack: 81920 outputs, 4 per thread
        int base = (bid - 11264) * 1024 + threadIdx.x * 4;
        #pragma unroll
        for (int j = 0; j < 4; j++) {
            int idx = base + j;
            int lvl = idx >> 13, rem = idx & 8191;
            int o = rem >> 7, ck = rem & 127;
            int k = ck >> 6, ci = ck & 63;
            dw[idx] = f2bf(cw[(lvl << 13) + (o << 7) + (ci << 1) + k]);
        }
        return;
    }
    const float* s; u16* d; int nt;
    if      (bid < 8192)  { s = s0; d = d0; nt = 2097152; }
    else if (bid < 8960)  { bid -= 8192;  s = s1; d = d1; nt = 196608; }
    else if (bid < 9216)  { bid -= 8960;  s = s2; d = d2; nt = 65536;  }
    else if (bid < 10240) { bid -= 9216;  s = s3; d = d3; nt = 262144; }
    else                  { bid -= 10240; s = s4; d = d4; nt = 262144; }
    int i = bid * 256 + threadIdx.x;
    if (i < nt) {
        float4 v = ((const float4*)s)[i];
        uint2 o;
        o.x = (uint32_t)f2bf(v.x) | ((uint32_t)f2bf(v.y) << 16);
        o.y = (uint32_t)f2bf(v.z) | ((uint32_t)f2bf(v.w) << 16);
        ((uint2*)d)[i] = o;
    }
}

// ---------------------------------------------------------------------------
// MFMA conv level: OUT[r, h*64+o] = relu(sum_{ck} A[r][ck]*W[o][ck] + b[o]),
// A[r][k*64+ci] = IN[2r+k, h*64+ci].  IN/OUT row-major (rows, 512) bf16.
// Block: 128 out-rows x 64 out-ch (one head). K=128, single pass.
// XOR swizzle (16B chunks) on A and B LDS to avoid 256B-stride conflicts:
// linear LDS dest via global_load_lds + pre-swizzled global source (m173).
// ---------------------------------------------------------------------------
__global__ __launch_bounds__(256, 2)
void conv_mfma_kernel(const u16* __restrict__ IN, u16* __restrict__ OUT,
                      const u16* __restrict__ WR, const float* __restrict__ bias,
                      int Min, int Mout)
{
    __shared__ u16 Asub[256 * 64];   // [input row][64 ci], 128B/row = 8 chunks
    __shared__ u16 Bsub[64 * 128];   // [o][128 ck], 256B/row = 16 chunks
    const int tid = threadIdx.x;
    const int l = tid & 63, w = tid >> 6;
    const int h  = blockIdx.x;
    const int r0 = blockIdx.y * 128;

    // stage A: rows 2*r0 .. 2*r0+255, cols h*64..h*64+63 (clamped)
    #pragma unroll
    for (int c = 0; c < 8; c++) {
        int G = (w * 8 + c) * 64 + l;
        int row = G >> 3, lch = G & 7;
        int gch = lch ^ ((row >> 1) & 7);
        int rg = 2 * r0 + row; if (rg > Min - 1) rg = Min - 1;
        gload16(IN + (size_t)rg * 512 + h * 64 + gch * 8,
                Asub + (size_t)(w * 8 + c) * 512);
    }
    // stage B: weights [64][128]
    #pragma unroll
    for (int c = 0; c < 4; c++) {
        int G = (w * 4 + c) * 64 + l;
        int o = G >> 4, lch = G & 15;
        int gch = lch ^ (o & 7);
        gload16(WR + o * 128 + gch * 8,
                Bsub + (size_t)(w * 4 + c) * 512);
    }
    __syncthreads();

    const int wm = w >> 1, wn = w & 1;
    const int g = l >> 4;
    f32x4 acc[4][2];
    #pragma unroll
    for (int m = 0; m < 4; m++)
        #pragma unroll
        for (int n = 0; n < 2; n++) acc[m][n] = 0.f;

    #pragma unroll
    for (int kt = 0; kt < 4; kt++) {
        const int k = kt >> 1;
        bf16x8 av[4], bv[2];
        #pragma unroll
        for (int m = 0; m < 4; m++) {
            int lr = wm * 64 + m * 16 + (l & 15);
            int il = 2 * lr + k;
            int ch = ((kt & 1) * 4 + g) ^ (lr & 7);
            av[m] = *(const bf16x8*)(Asub + il * 64 + ch * 8);
        }
        #pragma unroll
        for (int n = 0; n < 2; n++) {
            int o = wn * 32 + n * 16 + (l & 15);
            int ch = (kt * 4 + g) ^ (o & 7);
            bv[n] = *(const bf16x8*)(Bsub + o * 128 + ch * 8);
        }
        #pragma unroll
        for (int m = 0; m < 4; m++)
            #pragma unroll
            for (int n = 0; n < 2; n++)
                acc[m][n] = __builtin_amdgcn_mfma_f32_16x16x32_bf16(av[m], bv[n], acc[m][n], 0, 0, 0);
    }

    #pragma unroll
    for (int n = 0; n < 2; n++) {
        int o = wn * 32 + n * 16 + (l & 15);
        float bb = bias[o];
        #pragma unroll
        for (int m = 0; m < 4; m++) {
            #pragma unroll
            for (int reg = 0; reg < 4; reg++) {
                int row = r0 + wm * 64 + m * 16 + g * 4 + reg;
                if (row < Mout) {
                    float v = fmaxf(acc[m][n][reg] + bb, 0.f);
                    OUT[(size_t)row * 512 + h * 64 + o] = f2bf(v);
                }
            }
        }
    }
}

// ---------------------------------------------------------------------------
// bf16 MFMA GEMM (m97 structure), unchanged from round 2.
// ---------------------------------------------------------------------------
__global__ __launch_bounds__(256, 2)
void mfma_gemm(const u16* __restrict__ A, const u16* __restrict__ W,
               const float* __restrict__ bias, const float* __restrict__ residual,
               float* __restrict__ Cf, u16* __restrict__ Cb,
               int M, int K, int N, int relu)
{
    __shared__ u16 As[128 * 32];
    __shared__ u16 Bs[128 * 32];
    const int tid = threadIdx.x;
    const int l = tid & 63, w = tid >> 6;
    const int wm = w >> 1, wn = w & 1;
    const int rowBase = blockIdx.y * 128;
    const int colBase = blockIdx.x * 128;

    f32x4 acc[4][4];
    #pragma unroll
    for (int m = 0; m < 4; m++)
        #pragma unroll
        for (int n = 0; n < 4; n++) acc[m][n] = 0.f;

    int rA0 = rowBase + w * 16 + (l >> 2);        if (rA0 > M - 1) rA0 = M - 1;
    int rA1 = rowBase + 64 + w * 16 + (l >> 2);   if (rA1 > M - 1) rA1 = M - 1;
    const u16* gA0 = A + (size_t)rA0 * K + (l & 3) * 8;
    const u16* gA1 = A + (size_t)rA1 * K + (l & 3) * 8;
    const u16* gB0 = W + (size_t)(colBase + w * 16 + (l >> 2)) * K + (l & 3) * 8;
    const u16* gB1 = W + (size_t)(colBase + 64 + w * 16 + (l >> 2)) * K + (l & 3) * 8;
    u16* lA = As + w * 512;
    u16* lB = Bs + w * 512;

    for (int kt = 0; kt < K; kt += 32) {
        gload16(gA0 + kt, lA);
        gload16(gA1 + kt, lA + 64 * 32);
        gload16(gB0 + kt, lB);
        gload16(gB1 + kt, lB + 64 * 32);
        __syncthreads();

        const u16* pa = As + (wm * 64 + (l & 15)) * 32 + (l >> 4) * 8;
        const u16* pb = Bs + (wn * 64 + (l & 15)) * 32 + (l >> 4) * 8;
        bf16x8 av[4], bv[4];
        #pragma unroll
        for (int m = 0; m < 4; m++) av[m] = *(const bf16x8*)(pa + m * 512);
        #pragma unroll
        for (int n = 0; n < 4; n++) bv[n] = *(const bf16x8*)(pb + n * 512);
        #pragma unroll
        for (int m = 0; m < 4; m++)
            #pragma unroll
            for (int n = 0; n < 4; n++)
                acc[m][n] = __builtin_amdgcn_mfma_f32_16x16x32_bf16(av[m], bv[n], acc[m][n], 0, 0, 0);
        __syncthreads();
    }

    const int cc = colBase + wn * 64 + (l & 15);
    float bs4[4];
    #pragma unroll
    for (int n = 0; n < 4; n++) bs4[n] = bias[cc + n * 16];
    #pragma unroll
    for (int m = 0; m < 4; m++) {
        #pragma unroll
        for (int reg = 0; reg < 4; reg++) {
            int row = rowBase + wm * 64 + m * 16 + (l >> 4) * 4 + reg;
            if (row < M) {
                #pragma unroll
                for (int n = 0; n < 4; n++) {
                    int col = cc + n * 16;
                    float v = acc[m][n][reg] + bs4[n];
                    if (residual) v += residual[(size_t)row * N + col];
                    if (relu) v = fmaxf(v, 0.f);
                    if (Cb) Cb[(size_t)row * N + col] = f2bf(v);
                    else    Cf[(size_t)row * N + col] = v;
                }
            }
        }
    }
}

// ---------------------------------------------------------------------------
// Attention (bf16 in/out), unchanged from round 2.
// ---------------------------------------------------------------------------
__global__ void attn_kernel(const u16* __restrict__ QKV, const u16* __restrict__ KVs,
                            u16* __restrict__ O)
{
    const int wv   = threadIdx.x >> 6;
    const int lane = threadIdx.x & 63;
    const int b    = blockIdx.x * 4 + wv;
    const int h    = lane >> 3;
    const int d8   = lane & 7;
    const int n = b >> 10, pos = b & 1023;

    float q[8];
    ld8bf(QKV + (size_t)b * 1536 + h * 64 + d8 * 8, q);

    float sc[NSCALES];
    {
        float kk[8];
        ld8bf(QKV + (size_t)b * 1536 + 512 + h * 64 + d8 * 8, kk);
        float p = 0.f;
        #pragma unroll
        for (int j = 0; j < 8; j++) p += q[j] * kk[j];
        p += __shfl_xor(p, 1); p += __shfl_xor(p, 2); p += __shfl_xor(p, 4);
        sc[0] = p * 0.125f;
    }
    {
        int rowOff = 0;
        #pragma unroll
        for (int s = 1; s <= NLEVELS; s++) {
            int Ls = 1024 >> s;
            int row = rowOff + n * Ls + (pos >> s);
            float kk[8];
            ld8bf(KVs + (size_t)row * 1024 + h * 64 + d8 * 8, kk);
            float p = 0.f;
            #pragma unroll
            for (int j = 0; j < 8; j++) p += q[j] * kk[j];
            p += __shfl_xor(p, 1); p += __shfl_xor(p, 2); p += __shfl_xor(p, 4);
            sc[s] = p * 0.125f;
            rowOff += 16 * Ls;
        }
    }
    float m = sc[0];
    #pragma unroll
    for (int s = 1; s < NSCALES; s++) m = fmaxf(m, sc[s]);
    float sum = 0.f;
    #pragma unroll
    for (int s = 0; s < NSCALES; s++) { sc[s] = __expf(sc[s] - m); sum += sc[s]; }
    float inv = 1.f / sum;

    float o[8] = {};
    {
        float vv[8];
        ld8bf(QKV + (size_t)b * 1536 + 1024 + h * 64 + d8 * 8, vv);
        float a = sc[0] * inv;
        #pragma unroll
        for (int j = 0; j < 8; j++) o[j] += a * vv[j];
    }
    {
        int rowOff = 0;
        #pragma unroll
        for (int s = 1; s <= NLEVELS; s++) {
            int Ls = 1024 >> s;
            int row = rowOff + n * Ls + (pos >> s);
            float vv[8];
            ld8bf(KVs + (size_t)row * 1024 + 512 + h * 64 + d8 * 8, vv);
            float a = sc[s] * inv;
            #pragma unroll
            for (int j = 0; j < 8; j++) o[j] += a * vv[j];
            rowOff += 16 * Ls;
        }
    }
    uint4 pk;
    pk.x = (uint32_t)f2bf(o[0]) | ((uint32_t)f2bf(o[1]) << 16);
    pk.y = (uint32_t)f2bf(o[2]) | ((uint32_t)f2bf(o[3]) << 16);
    pk.z = (uint32_t)f2bf(o[4]) | ((uint32_t)f2bf(o[5]) << 16);
    pk.w = (uint32_t)f2bf(o[6]) | ((uint32_t)f2bf(o[7]) << 16);
    *(uint4*)(O + (size_t)b * 512 + h * 64 + d8 * 8) = pk;
}

// ---------------------------------------------------------------------------
// LayerNorm over E=512; optional secondary bf16 output.
// ---------------------------------------------------------------------------
__global__ void ln_kernel(const float* __restrict__ in, float* __restrict__ out,
                          const float* __restrict__ w, const float* __restrict__ b,
                          u16* __restrict__ out_bf)
{
    const int row = blockIdx.x;
    const int tid = threadIdx.x;
    float2 v = *(const float2*)&in[(size_t)row * EE + tid * 2];
    float s  = v.x + v.y;
    float s2 = v.x * v.x + v.y * v.y;
    #pragma unroll
    for (int m = 1; m < 64; m <<= 1) { s += __shfl_xor(s, m); s2 += __shfl_xor(s2, m); }
    __shared__ float ss[4], ss2[4];
    int wv = tid >> 6;
    if ((tid & 63) == 0) { ss[wv] = s; ss2[wv] = s2; }
    __syncthreads();
    s  = ss[0] + ss[1] + ss[2] + ss[3];
    s2 = ss2[0] + ss2[1] + ss2[2] + ss2[3];
    float mu  = s * (1.f / 512.f);
    float var = s2 * (1.f / 512.f) - mu * mu;
    float rs  = rsqrtf(var + 1e-5f);
    float2 o;
    o.x = (v.x - mu) * rs * w[tid * 2]     + b[tid * 2];
    o.y = (v.y - mu) * rs * w[tid * 2 + 1] + b[tid * 2 + 1];
    *(float2*)&out[(size_t)row * EE + tid * 2] = o;
    if (out_bf) {
        uint32_t pk = (uint32_t)f2bf(o.x) | ((uint32_t)f2bf(o.y) << 16);
        *(uint32_t*)&out_bf[(size_t)row * EE + tid * 2] = pk;
    }
}

// ---------------------------------------------------------------------------
extern "C" void kernel_launch(void* const* d_in, const int* in_sizes, int n_in,
                              void* d_out, int out_size, void* d_ws, size_t ws_size,
                              hipStream_t stream)
{
    const float* src        = (const float*)d_in[0];
    const float* conv_w     = (const float*)d_in[1];
    const float* conv_b     = (const float*)d_in[2];
    const float* in_proj_w  = (const float*)d_in[3];
    const float* in_proj_b  = (const float*)d_in[4];
    const float* out_proj_w = (const float*)d_in[5];
    const float* out_proj_b = (const float*)d_in[6];
    const float* ln1_w      = (const float*)d_in[7];
    const float* ln1_b      = (const float*)d_in[8];
    const float* ln2_w      = (const float*)d_in[9];
    const float* ln2_b      = (const float*)d_in[10];
    const float* w1         = (const float*)d_in[11];
    const float* b1         = (const float*)d_in[12];
    const float* w2         = (const float*)d_in[13];
    const float* b2         = (const float*)d_in[14];

    char*  wsb    = (char*)d_ws;
    float* out    = (float*)d_out;
    u16*   src_bf = (u16*)(wsb + B_SRCBF);
    u16*   lvl_bf = (u16*)(wsb + B_LVLBF);
    u16*   QKV    = (u16*)(wsb + B_QKV);
    u16*   KVs    = (u16*)(wsb + B_KVS);
    u16*   O_bf   = (u16*)(wsb + B_OBF);
    float* X      = (float*)(wsb + B_X);
    u16*   X_bf   = (u16*)(wsb + B_XBF);
    u16*   inw_bf = (u16*)(wsb + B_WBF);
    u16*   outw_bf= inw_bf + 786432;
    u16*   w1_bf  = outw_bf + 262144;
    u16*   w2_bf  = w1_bf + 1048576;
    u16*   cw_bf  = w2_bf + 1048576;     // 81920 elems, (lvl, o, k*64+ci)
    u16*   FFH    = (u16*)(wsb + B_FFH);

    // 0) cast src + weights to bf16 (+ conv_w repack)
    cast_all_kernel<<<11344, 256, 0, stream>>>(src, in_proj_w, out_proj_w, w1, w2, conv_w,
                                               src_bf, inw_bf, outw_bf, w1_bf, w2_bf, cw_bf);

    // 1) conv pyramid via MFMA; levels write row-major bf16 directly into lvl_bf
    {
        const u16* inp = src_bf;
        int Tin = LL;
        size_t rowOff = 0;
        for (int i = 0; i < NLEVELS; i++) {
            int T = Tin >> 1;
            int Mout = NB * T, Min = NB * Tin;
            u16* outp = lvl_bf + rowOff * EE;
            dim3 g(NHEADS, (Mout + 127) / 128);
            conv_mfma_kernel<<<g, 256, 0, stream>>>(
                inp, outp, cw_bf + (size_t)i * 8192, conv_b + (size_t)i * 64, Min, Mout);
            inp = outp;
            rowOff += Mout;
            Tin = T;
        }
    }

    // 2) QKV = src_bf @ in_proj_w^T + b  (16384 x 1536)
    mfma_gemm<<<dim3(12, 128), 256, 0, stream>>>(
        src_bf, inw_bf, in_proj_b, nullptr, nullptr, QKV, BROWS, EE, 1536, 0);

    // 3) KVs = lvl_bf @ Wkv^T + b_kv  (16368 x 1024)
    mfma_gemm<<<dim3(8, 128), 256, 0, stream>>>(
        lvl_bf, inw_bf + (size_t)512 * 512, in_proj_b + 512, nullptr, nullptr, KVs,
        16368, EE, 1024, 0);

    // 4) attention -> O_bf
    attn_kernel<<<BROWS / 4, 256, 0, stream>>>(QKV, KVs, O_bf);

    // 5) X = O_bf @ out_proj^T + b  (fp32)
    mfma_gemm<<<dim3(4, 128), 256, 0, stream>>>(
        O_bf, outw_bf, out_proj_b, nullptr, X, nullptr, BROWS, EE, EE, 0);

    // 6) LN1 in place (+ bf16 copy)
    ln_kernel<<<BROWS, 256, 0, stream>>>(X, X, ln1_w, ln1_b, X_bf);

    // 7) FFH = relu(X_bf @ w1^T + b1)  (bf16)
    mfma_gemm<<<dim3(16, 128), 256, 0, stream>>>(
        X_bf, w1_bf, b1, nullptr, nullptr, FFH, BROWS, EE, DFF, 1);

    // 8) out = FFH @ w2^T + b2 + X  (fp32)
    mfma_gemm<<<dim3(4, 128), 256, 0, stream>>>(
        FFH, w2_bf, b2, X, out, nullptr, BROWS, DFF, EE, 0);

    // 9) LN2 in place on out
    ln_kernel<<<BROWS, 256, 0, stream>>>(out, out, ln2_w, ln2_b, nullptr);
}

// Round 4
// 306.096 us; speedup vs baseline: 10.1408x; 1.2192x over previous
//
#include <hip/hip_runtime.h>
#include <hip/hip_bf16.h>
#include <stdint.h>
#include <math.h>

// Problem constants
#define NB      16
#define LL      1024
#define EE      512
#define NHEADS  8
#define DFF     2048
#define NLEVELS 10
#define NSCALES 11
#define BROWS   (NB * LL)       // 16384

typedef unsigned short u16;
typedef __attribute__((ext_vector_type(8))) short bf16x8;   // 8 bf16 = 4 VGPRs (MFMA A/B frag)
typedef __attribute__((ext_vector_type(4))) float f32x4;    // MFMA C/D frag

// ---------------- workspace layout (byte offsets) ----------------
static const size_t B_SRCBF = 0;                         // 16,777,216
static const size_t B_LVLBF = 16777216;                  // 16,760,832
static const size_t B_QKV   = 33538048;                  // 50,331,648
static const size_t B_KVS   = 83869696;                  // 33,521,664
static const size_t B_OBF   = 117391360;                 // 16,777,216
static const size_t B_X     = 134168576;                 // 33,554,432
static const size_t B_XBF   = 167723008;                 // 16,777,216
static const size_t B_WBF   = 184500224;                 // weights
static const size_t B_FFH   = 0;                         // overlaps dead-by-then buffers

// ---------------- helpers ----------------
__device__ __forceinline__ u16 f2bf(float x) {
    union { float f; uint32_t u; } c; c.f = x;
    uint32_t u = c.u + 0x7FFFu + ((c.u >> 16) & 1u);
    return (u16)(u >> 16);
}
__device__ __forceinline__ void ld8bf(const u16* p, float* f) {
    uint4 r = *(const uint4*)p;
    uint32_t ws[4] = { r.x, r.y, r.z, r.w };
    #pragma unroll
    for (int j = 0; j < 4; j++) {
        union { uint32_t u; float g; } lo, hi;
        lo.u = ws[j] << 16; hi.u = ws[j] & 0xFFFF0000u;
        f[2 * j] = lo.g; f[2 * j + 1] = hi.g;
    }
}
__device__ __forceinline__ void gload16(const u16* g, u16* l) {
    __builtin_amdgcn_global_load_lds(
        (const __attribute__((address_space(1))) void*)g,
        (__attribute__((address_space(3))) void*)l, 16, 0, 0);
}

// ---------------------------------------------------------------------------
// Fused cast kernel: src + 4 weight tensors -> bf16, plus conv_w repack.
// ---------------------------------------------------------------------------
__global__ void cast_all_kernel(const float* __restrict__ s0, const float* __restrict__ s1,
                                const float* __restrict__ s2, const float* __restrict__ s3,
                                const float* __restrict__ s4, const float* __restrict__ cw,
                                u16* __restrict__ d0, u16* __restrict__ d1,
                                u16* __restrict__ d2, u16* __restrict__ d3,
                                u16* __restrict__ d4, u16* __restrict__ dw)
{
    int bid = blockIdx.x;
    if (bid >= 11264) {   // conv_w repack: 81920 outputs
        int base = (bid - 11264) * 1024 + threadIdx.x * 4;
        #pragma unroll
        for (int j = 0; j < 4; j++) {
            int idx = base + j;
            int lvl = idx >> 13, rem = idx & 8191;
            int o = rem >> 7, ck = rem & 127;
            int k = ck >> 6, ci = ck & 63;
            dw[idx] = f2bf(cw[(lvl << 13) + (o << 7) + (ci << 1) + k]);
        }
        return;
    }
    const float* s; u16* d; int nt;
    if      (bid < 8192)  { s = s0; d = d0; nt = 2097152; }
    else if (bid < 8960)  { bid -= 8192;  s = s1; d = d1; nt = 196608; }
    else if (bid < 9216)  { bid -= 8960;  s = s2; d = d2; nt = 65536;  }
    else if (bid < 10240) { bid -= 9216;  s = s3; d = d3; nt = 262144; }
    else                  { bid -= 10240; s = s4; d = d4; nt = 262144; }
    int i = bid * 256 + threadIdx.x;
    if (i < nt) {
        float4 v = ((const float4*)s)[i];
        uint2 o;
        o.x = (uint32_t)f2bf(v.x) | ((uint32_t)f2bf(v.y) << 16);
        o.y = (uint32_t)f2bf(v.z) | ((uint32_t)f2bf(v.w) << 16);
        ((uint2*)d)[i] = o;
    }
}

// ---------------------------------------------------------------------------
// MFMA conv level (unchanged from round 3)
// ---------------------------------------------------------------------------
__global__ __launch_bounds__(256, 2)
void conv_mfma_kernel(const u16* __restrict__ IN, u16* __restrict__ OUT,
                      const u16* __restrict__ WR, const float* __restrict__ bias,
                      int Min, int Mout)
{
    __shared__ u16 Asub[256 * 64];
    __shared__ u16 Bsub[64 * 128];
    const int tid = threadIdx.x;
    const int l = tid & 63, w = tid >> 6;
    const int h  = blockIdx.x;
    const int r0 = blockIdx.y * 128;

    #pragma unroll
    for (int c = 0; c < 8; c++) {
        int G = (w * 8 + c) * 64 + l;
        int row = G >> 3, lch = G & 7;
        int gch = lch ^ ((row >> 1) & 7);
        int rg = 2 * r0 + row; if (rg > Min - 1) rg = Min - 1;
        gload16(IN + (size_t)rg * 512 + h * 64 + gch * 8,
                Asub + (size_t)(w * 8 + c) * 512);
    }
    #pragma unroll
    for (int c = 0; c < 4; c++) {
        int G = (w * 4 + c) * 64 + l;
        int o = G >> 4, lch = G & 15;
        int gch = lch ^ (o & 7);
        gload16(WR + o * 128 + gch * 8,
                Bsub + (size_t)(w * 4 + c) * 512);
    }
    __syncthreads();

    const int wm = w >> 1, wn = w & 1;
    const int g = l >> 4;
    f32x4 acc[4][2];
    #pragma unroll
    for (int m = 0; m < 4; m++)
        #pragma unroll
        for (int n = 0; n < 2; n++) acc[m][n] = 0.f;

    #pragma unroll
    for (int kt = 0; kt < 4; kt++) {
        const int k = kt >> 1;
        bf16x8 av[4], bv[2];
        #pragma unroll
        for (int m = 0; m < 4; m++) {
            int lr = wm * 64 + m * 16 + (l & 15);
            int il = 2 * lr + k;
            int ch = ((kt & 1) * 4 + g) ^ (lr & 7);
            av[m] = *(const bf16x8*)(Asub + il * 64 + ch * 8);
        }
        #pragma unroll
        for (int n = 0; n < 2; n++) {
            int o = wn * 32 + n * 16 + (l & 15);
            int ch = (kt * 4 + g) ^ (o & 7);
            bv[n] = *(const bf16x8*)(Bsub + o * 128 + ch * 8);
        }
        #pragma unroll
        for (int m = 0; m < 4; m++)
            #pragma unroll
            for (int n = 0; n < 2; n++)
                acc[m][n] = __builtin_amdgcn_mfma_f32_16x16x32_bf16(av[m], bv[n], acc[m][n], 0, 0, 0);
    }

    #pragma unroll
    for (int n = 0; n < 2; n++) {
        int o = wn * 32 + n * 16 + (l & 15);
        float bb = bias[o];
        #pragma unroll
        for (int m = 0; m < 4; m++) {
            #pragma unroll
            for (int reg = 0; reg < 4; reg++) {
                int row = r0 + wm * 64 + m * 16 + g * 4 + reg;
                if (row < Mout) {
                    float v = fmaxf(acc[m][n][reg] + bb, 0.f);
                    OUT[(size_t)row * 512 + h * 64 + o] = f2bf(v);
                }
            }
        }
    }
}

// ---------------------------------------------------------------------------
// bf16 MFMA GEMM, 128x128 tile, BK=32:
//  + XCD-chunked bijective block swizzle (1-D grid, m204)
//  + 2-phase double-buffered global_load_lds with counted vmcnt(4)
//  + vectorized epilogue via per-wave LDS transpose (XOR bank swizzle)
// ---------------------------------------------------------------------------
__global__ __launch_bounds__(256, 2)
void mfma_gemm(const u16* __restrict__ A, const u16* __restrict__ W,
               const float* __restrict__ bias, const float* __restrict__ residual,
               float* __restrict__ Cf, u16* __restrict__ Cb,
               int M, int K, int N, int relu, int gx)
{
    __shared__ u16 lds[16384];   // 32 KB: 2x(A 8KB + B 8KB); reused by epilogue
    const int tid = threadIdx.x;
    const int l = tid & 63, w = tid >> 6;
    const int wm = w >> 1, wn = w & 1;

    // XCD-chunked bijective swizzle: row-major lin order, contiguous chunk per XCD
    const int nwg = gridDim.x;
    const int q = nwg >> 3, r = nwg & 7;
    const int xcd = blockIdx.x & 7, idx = blockIdx.x >> 3;
    const int lin = (xcd < r ? xcd * (q + 1) : r * (q + 1) + (xcd - r) * q) + idx;
    const int by = lin / gx, bx = lin - by * gx;
    const int rowBase = by * 128, colBase = bx * 128;

    f32x4 acc[4][4];
    #pragma unroll
    for (int m = 0; m < 4; m++)
        #pragma unroll
        for (int n = 0; n < 4; n++) acc[m][n] = 0.f;

    int rA0 = rowBase + w * 16 + (l >> 2);        if (rA0 > M - 1) rA0 = M - 1;
    int rA1 = rowBase + 64 + w * 16 + (l >> 2);   if (rA1 > M - 1) rA1 = M - 1;
    const u16* gA0 = A + (size_t)rA0 * K + (l & 3) * 8;
    const u16* gA1 = A + (size_t)rA1 * K + (l & 3) * 8;
    const u16* gB0 = W + (size_t)(colBase + w * 16 + (l >> 2)) * K + (l & 3) * 8;
    const u16* gB1 = W + (size_t)(colBase + 64 + w * 16 + (l >> 2)) * K + (l & 3) * 8;

    const int NT = K >> 5;
    {   // prologue: stage K-tile 0 into buf 0
        u16* d = lds + w * 512;
        gload16(gA0, d);
        gload16(gA1, d + 2048);
        gload16(gB0, d + 4096);
        gload16(gB1, d + 4096 + 2048);
    }
    for (int t = 0; t < NT; ++t) {
        if (t + 1 < NT) {   // prefetch next K-tile into other buffer
            const int kb = (t + 1) << 5;
            u16* d = lds + ((t + 1) & 1) * 8192 + w * 512;
            gload16(gA0 + kb, d);
            gload16(gA1 + kb, d + 2048);
            gload16(gB0 + kb, d + 4096);
            gload16(gB1 + kb, d + 4096 + 2048);
            asm volatile("s_waitcnt vmcnt(4)" ::: "memory");   // current tile landed
        } else {
            asm volatile("s_waitcnt vmcnt(0)" ::: "memory");
        }
        __builtin_amdgcn_s_barrier();
        __builtin_amdgcn_sched_barrier(0);

        const u16* bufc = lds + (t & 1) * 8192;
        const u16* pa = bufc + (wm * 64 + (l & 15)) * 32 + (l >> 4) * 8;
        const u16* pb = bufc + 4096 + (wn * 64 + (l & 15)) * 32 + (l >> 4) * 8;
        bf16x8 av[4], bv[4];
        #pragma unroll
        for (int m = 0; m < 4; m++) av[m] = *(const bf16x8*)(pa + m * 512);
        #pragma unroll
        for (int n = 0; n < 4; n++) bv[n] = *(const bf16x8*)(pb + n * 512);
        #pragma unroll
        for (int m = 0; m < 4; m++)
            #pragma unroll
            for (int n = 0; n < 4; n++)
                acc[m][n] = __builtin_amdgcn_mfma_f32_16x16x32_bf16(av[m], bv[n], acc[m][n], 0, 0, 0);

        __builtin_amdgcn_sched_barrier(0);
        __builtin_amdgcn_s_barrier();   // all waves done reading bufc
        __builtin_amdgcn_sched_barrier(0);
    }

    // ---- epilogue: per-wave LDS transpose -> coalesced vector stores ----
    const int cc = colBase + wn * 64 + (l & 15);
    float bs4[4];
    #pragma unroll
    for (int n = 0; n < 4; n++) bs4[n] = bias[cc + n * 16];

    if (Cb) {
        u16* WS = lds + w * 2048;   // 4 KB/wave (32 rows x 64 cols u16)
        #pragma unroll
        for (int hh = 0; hh < 2; hh++) {
            #pragma unroll
            for (int mi = 0; mi < 2; mi++) {
                #pragma unroll
                for (int n = 0; n < 4; n++) {
                    int colv = n * 16 + (l & 15);
                    #pragma unroll
                    for (int reg = 0; reg < 4; reg++) {
                        int rowh = mi * 16 + (l >> 4) * 4 + reg;
                        float v = acc[hh * 2 + mi][n][reg] + bs4[n];
                        if (relu) v = fmaxf(v, 0.f);
                        WS[rowh * 64 + (colv ^ (((rowh >> 2) & 3) << 4))] = f2bf(v);
                    }
                }
            }
            asm volatile("s_waitcnt lgkmcnt(0)" ::: "memory");
            __builtin_amdgcn_sched_barrier(0);
            #pragma unroll
            for (int j = 0; j < 4; j++) {
                int rowh = (l >> 3) + 8 * j;
                int col8 = (l & 7) * 8;
                int colx = col8 ^ (((rowh >> 2) & 3) << 4);
                uint4 v = *(const uint4*)(WS + rowh * 64 + colx);
                int grow = rowBase + wm * 64 + hh * 32 + rowh;
                if (grow < M)
                    *(uint4*)(Cb + (size_t)grow * N + colBase + wn * 64 + col8) = v;
            }
        }
    } else {
        float* WSf = (float*)lds + w * 2048;   // 8 KB/wave (32 rows x 64 cols f32)
        #pragma unroll
        for (int hh = 0; hh < 2; hh++) {
            #pragma unroll
            for (int mi = 0; mi < 2; mi++) {
                #pragma unroll
                for (int n = 0; n < 4; n++) {
                    int colv = n * 16 + (l & 15);
                    #pragma unroll
                    for (int reg = 0; reg < 4; reg++) {
                        int rowh = mi * 16 + (l >> 4) * 4 + reg;
                        WSf[rowh * 64 + (colv ^ (((rowh >> 2) & 3) << 4))] =
                            acc[hh * 2 + mi][n][reg] + bs4[n];
                    }
                }
            }
            asm volatile("s_waitcnt lgkmcnt(0)" ::: "memory");
            __builtin_amdgcn_sched_barrier(0);
            #pragma unroll
            for (int j = 0; j < 8; j++) {
                int rowh = (l >> 4) + 4 * j;
                int col4 = (l & 15) * 4;
                int colx = col4 ^ (((rowh >> 2) & 3) << 4);
                float4 v = *(const float4*)(WSf + rowh * 64 + colx);
                int grow = rowBase + wm * 64 + hh * 32 + rowh;
                if (grow < M) {
                    int gcol = colBase + wn * 64 + col4;
                    if (residual) {
                        float4 rr = *(const float4*)&residual[(size_t)grow * N + gcol];
                        v.x += rr.x; v.y += rr.y; v.z += rr.z; v.w += rr.w;
                    }
                    if (relu) {
                        v.x = fmaxf(v.x, 0.f); v.y = fmaxf(v.y, 0.f);
                        v.z = fmaxf(v.z, 0.f); v.w = fmaxf(v.w, 0.f);
                    }
                    *(float4*)&Cf[(size_t)grow * N + gcol] = v;
                }
            }
        }
    }
}

// ---------------------------------------------------------------------------
// Attention (bf16 in/out), unchanged.
// ---------------------------------------------------------------------------
__global__ void attn_kernel(const u16* __restrict__ QKV, const u16* __restrict__ KVs,
                            u16* __restrict__ O)
{
    const int wv   = threadIdx.x >> 6;
    const int lane = threadIdx.x & 63;
    const int b    = blockIdx.x * 4 + wv;
    const int h    = lane >> 3;
    const int d8   = lane & 7;
    const int n = b >> 10, pos = b & 1023;

    float q[8];
    ld8bf(QKV + (size_t)b * 1536 + h * 64 + d8 * 8, q);

    float sc[NSCALES];
    {
        float kk[8];
        ld8bf(QKV + (size_t)b * 1536 + 512 + h * 64 + d8 * 8, kk);
        float p = 0.f;
        #pragma unroll
        for (int j = 0; j < 8; j++) p += q[j] * kk[j];
        p += __shfl_xor(p, 1); p += __shfl_xor(p, 2); p += __shfl_xor(p, 4);
        sc[0] = p * 0.125f;
    }
    {
        int rowOff = 0;
        #pragma unroll
        for (int s = 1; s <= NLEVELS; s++) {
            int Ls = 1024 >> s;
            int row = rowOff + n * Ls + (pos >> s);
            float kk[8];
            ld8bf(KVs + (size_t)row * 1024 + h * 64 + d8 * 8, kk);
            float p = 0.f;
            #pragma unroll
            for (int j = 0; j < 8; j++) p += q[j] * kk[j];
            p += __shfl_xor(p, 1); p += __shfl_xor(p, 2); p += __shfl_xor(p, 4);
            sc[s] = p * 0.125f;
            rowOff += 16 * Ls;
        }
    }
    float m = sc[0];
    #pragma unroll
    for (int s = 1; s < NSCALES; s++) m = fmaxf(m, sc[s]);
    float sum = 0.f;
    #pragma unroll
    for (int s = 0; s < NSCALES; s++) { sc[s] = __expf(sc[s] - m); sum += sc[s]; }
    float inv = 1.f / sum;

    float o[8] = {};
    {
        float vv[8];
        ld8bf(QKV + (size_t)b * 1536 + 1024 + h * 64 + d8 * 8, vv);
        float a = sc[0] * inv;
        #pragma unroll
        for (int j = 0; j < 8; j++) o[j] += a * vv[j];
    }
    {
        int rowOff = 0;
        #pragma unroll
        for (int s = 1; s <= NLEVELS; s++) {
            int Ls = 1024 >> s;
            int row = rowOff + n * Ls + (pos >> s);
            float vv[8];
            ld8bf(KVs + (size_t)row * 1024 + 512 + h * 64 + d8 * 8, vv);
            float a = sc[s] * inv;
            #pragma unroll
            for (int j = 0; j < 8; j++) o[j] += a * vv[j];
            rowOff += 16 * Ls;
        }
    }
    uint4 pk;
    pk.x = (uint32_t)f2bf(o[0]) | ((uint32_t)f2bf(o[1]) << 16);
    pk.y = (uint32_t)f2bf(o[2]) | ((uint32_t)f2bf(o[3]) << 16);
    pk.z = (uint32_t)f2bf(o[4]) | ((uint32_t)f2bf(o[5]) << 16);
    pk.w = (uint32_t)f2bf(o[6]) | ((uint32_t)f2bf(o[7]) << 16);
    *(uint4*)(O + (size_t)b * 512 + h * 64 + d8 * 8) = pk;
}

// ---------------------------------------------------------------------------
// LayerNorm over E=512; optional secondary bf16 output.
// ---------------------------------------------------------------------------
__global__ void ln_kernel(const float* __restrict__ in, float* __restrict__ out,
                          const float* __restrict__ w, const float* __restrict__ b,
                          u16* __restrict__ out_bf)
{
    const int row = blockIdx.x;
    const int tid = threadIdx.x;
    float2 v = *(const float2*)&in[(size_t)row * EE + tid * 2];
    float s  = v.x + v.y;
    float s2 = v.x * v.x + v.y * v.y;
    #pragma unroll
    for (int m = 1; m < 64; m <<= 1) { s += __shfl_xor(s, m); s2 += __shfl_xor(s2, m); }
    __shared__ float ss[4], ss2[4];
    int wv = tid >> 6;
    if ((tid & 63) == 0) { ss[wv] = s; ss2[wv] = s2; }
    __syncthreads();
    s  = ss[0] + ss[1] + ss[2] + ss[3];
    s2 = ss2[0] + ss2[1] + ss2[2] + ss2[3];
    float mu  = s * (1.f / 512.f);
    float var = s2 * (1.f / 512.f) - mu * mu;
    float rs  = rsqrtf(var + 1e-5f);
    float2 o;
    o.x = (v.x - mu) * rs * w[tid * 2]     + b[tid * 2];
    o.y = (v.y - mu) * rs * w[tid * 2 + 1] + b[tid * 2 + 1];
    *(float2*)&out[(size_t)row * EE + tid * 2] = o;
    if (out_bf) {
        uint32_t pk = (uint32_t)f2bf(o.x) | ((uint32_t)f2bf(o.y) << 16);
        *(uint32_t*)&out_bf[(size_t)row * EE + tid * 2] = pk;
    }
}

// ---------------------------------------------------------------------------
extern "C" void kernel_launch(void* const* d_in, const int* in_sizes, int n_in,
                              void* d_out, int out_size, void* d_ws, size_t ws_size,
                              hipStream_t stream)
{
    const float* src        = (const float*)d_in[0];
    const float* conv_w     = (const float*)d_in[1];
    const float* conv_b     = (const float*)d_in[2];
    const float* in_proj_w  = (const float*)d_in[3];
    const float* in_proj_b  = (const float*)d_in[4];
    const float* out_proj_w = (const float*)d_in[5];
    const float* out_proj_b = (const float*)d_in[6];
    const float* ln1_w      = (const float*)d_in[7];
    const float* ln1_b      = (const float*)d_in[8];
    const float* ln2_w      = (const float*)d_in[9];
    const float* ln2_b      = (const float*)d_in[10];
    const float* w1         = (const float*)d_in[11];
    const float* b1         = (const float*)d_in[12];
    const float* w2         = (const float*)d_in[13];
    const float* b2         = (const float*)d_in[14];

    char*  wsb    = (char*)d_ws;
    float* out    = (float*)d_out;
    u16*   src_bf = (u16*)(wsb + B_SRCBF);
    u16*   lvl_bf = (u16*)(wsb + B_LVLBF);
    u16*   QKV    = (u16*)(wsb + B_QKV);
    u16*   KVs    = (u16*)(wsb + B_KVS);
    u16*   O_bf   = (u16*)(wsb + B_OBF);
    float* X      = (float*)(wsb + B_X);
    u16*   X_bf   = (u16*)(wsb + B_XBF);
    u16*   inw_bf = (u16*)(wsb + B_WBF);
    u16*   outw_bf= inw_bf + 786432;
    u16*   w1_bf  = outw_bf + 262144;
    u16*   w2_bf  = w1_bf + 1048576;
    u16*   cw_bf  = w2_bf + 1048576;
    u16*   FFH    = (u16*)(wsb + B_FFH);

    // 0) cast src + weights to bf16 (+ conv_w repack)
    cast_all_kernel<<<11344, 256, 0, stream>>>(src, in_proj_w, out_proj_w, w1, w2, conv_w,
                                               src_bf, inw_bf, outw_bf, w1_bf, w2_bf, cw_bf);

    // 1) conv pyramid via MFMA; row-major bf16 levels
    {
        const u16* inp = src_bf;
        int Tin = LL;
        size_t rowOff = 0;
        for (int i = 0; i < NLEVELS; i++) {
            int T = Tin >> 1;
            int Mout = NB * T, Min = NB * Tin;
            u16* outp = lvl_bf + rowOff * EE;
            dim3 g(NHEADS, (Mout + 127) / 128);
            conv_mfma_kernel<<<g, 256, 0, stream>>>(
                inp, outp, cw_bf + (size_t)i * 8192, conv_b + (size_t)i * 64, Min, Mout);
            inp = outp;
            rowOff += Mout;
            Tin = T;
        }
    }

    // 2) QKV = src_bf @ in_proj_w^T + b  (16384 x 1536), gx=12
    mfma_gemm<<<12 * 128, 256, 0, stream>>>(
        src_bf, inw_bf, in_proj_b, nullptr, nullptr, QKV, BROWS, EE, 1536, 0, 12);

    // 3) KVs = lvl_bf @ Wkv^T + b_kv  (16368 x 1024), gx=8
    mfma_gemm<<<8 * 128, 256, 0, stream>>>(
        lvl_bf, inw_bf + (size_t)512 * 512, in_proj_b + 512, nullptr, nullptr, KVs,
        16368, EE, 1024, 0, 8);

    // 4) attention -> O_bf
    attn_kernel<<<BROWS / 4, 256, 0, stream>>>(QKV, KVs, O_bf);

    // 5) X = O_bf @ out_proj^T + b  (fp32), gx=4
    mfma_gemm<<<4 * 128, 256, 0, stream>>>(
        O_bf, outw_bf, out_proj_b, nullptr, X, nullptr, BROWS, EE, EE, 0, 4);

    // 6) LN1 in place (+ bf16 copy)
    ln_kernel<<<BROWS, 256, 0, stream>>>(X, X, ln1_w, ln1_b, X_bf);

    // 7) FFH = relu(X_bf @ w1^T + b1)  (bf16), gx=16
    mfma_gemm<<<16 * 128, 256, 0, stream>>>(
        X_bf, w1_bf, b1, nullptr, nullptr, FFH, BROWS, EE, DFF, 1, 16);

    // 8) out = FFH @ w2^T + b2 + X  (fp32), gx=4
    mfma_gemm<<<4 * 128, 256, 0, stream>>>(
        FFH, w2_bf, b2, X, out, nullptr, BROWS, DFF, EE, 0, 4);

    // 9) LN2 in place on out
    ln_kernel<<<BROWS, 256, 0, stream>>>(out, out, ln2_w, ln2_b, nullptr);
}

// Round 6
// 283.388 us; speedup vs baseline: 10.9533x; 1.0801x over previous
//
#include <hip/hip_runtime.h>
#include <hip/hip_bf16.h>
#include <stdint.h>
#include <math.h>

// Problem constants
#define NB      16
#define LL      1024
#define EE      512
#define NHEADS  8
#define DFF     2048
#define NLEVELS 10
#define NSCALES 11
#define BROWS   (NB * LL)       // 16384

typedef unsigned short u16;
typedef __attribute__((ext_vector_type(8))) short bf16x8;   // 8 bf16 = 4 VGPRs (MFMA A/B frag)
typedef __attribute__((ext_vector_type(4))) float f32x4;    // MFMA C/D frag

// ---------------- workspace layout (byte offsets) ----------------
static const size_t B_SRCBF = 0;                         // 16,777,216
static const size_t B_LVLBF = 16777216;                  // 16,760,832
static const size_t B_QKV   = 33538048;                  // 50,331,648
static const size_t B_KVS   = 83869696;                  // 33,521,664
static const size_t B_OBF   = 117391360;                 // 16,777,216
static const size_t B_X     = 134168576;                 // 33,554,432
static const size_t B_XBF   = 167723008;                 // 16,777,216
static const size_t B_WBF   = 184500224;                 // weights
static const size_t B_FFH   = 0;                         // overlaps dead-by-then buffers

// ---------------- helpers ----------------
__device__ __forceinline__ u16 f2bf(float x) {
    union { float f; uint32_t u; } c; c.f = x;
    uint32_t u = c.u + 0x7FFFu + ((c.u >> 16) & 1u);
    return (u16)(u >> 16);
}
__device__ __forceinline__ float bf2f(u16 v) {
    union { uint32_t u; float f; } c; c.u = ((uint32_t)v) << 16; return c.f;
}
__device__ __forceinline__ void ld8bf(const u16* p, float* f) {
    uint4 r = *(const uint4*)p;
    uint32_t ws[4] = { r.x, r.y, r.z, r.w };
    #pragma unroll
    for (int j = 0; j < 4; j++) {
        union { uint32_t u; float g; } lo, hi;
        lo.u = ws[j] << 16; hi.u = ws[j] & 0xFFFF0000u;
        f[2 * j] = lo.g; f[2 * j + 1] = hi.g;
    }
}
__device__ __forceinline__ void gload16(const u16* g, u16* l) {
    __builtin_amdgcn_global_load_lds(
        (const __attribute__((address_space(1))) void*)g,
        (__attribute__((address_space(3))) void*)l, 16, 0, 0);
}

// ---------------------------------------------------------------------------
// Fused cast kernel: src + 4 weight tensors -> bf16, plus conv_w repack:
// wr[lvl][o][k*64+ci] = conv_w[lvl][o][ci][k].
// ---------------------------------------------------------------------------
__global__ void cast_all_kernel(const float* __restrict__ s0, const float* __restrict__ s1,
                                const float* __restrict__ s2, const float* __restrict__ s3,
                                const float* __restrict__ s4, const float* __restrict__ cw,
                                u16* __restrict__ d0, u16* __restrict__ d1,
                                u16* __restrict__ d2, u16* __restrict__ d3,
                                u16* __restrict__ d4, u16* __restrict__ dw)
{
    int bid = blockIdx.x;
    if (bid >= 11264) {   // conv_w repack: 81920 outputs
        int base = (bid - 11264) * 1024 + threadIdx.x * 4;
        #pragma unroll
        for (int j = 0; j < 4; j++) {
            int idx = base + j;
            int lvl = idx >> 13, rem = idx & 8191;
            int o = rem >> 7, ck = rem & 127;
            int k = ck >> 6, ci = ck & 63;
            dw[idx] = f2bf(cw[(lvl << 13) + (o << 7) + (ci << 1) + k]);
        }
        return;
    }
    const float* s; u16* d; int nt;
    if      (bid < 8192)  { s = s0; d = d0; nt = 2097152; }
    else if (bid < 8960)  { bid -= 8192;  s = s1; d = d1; nt = 196608; }
    else if (bid < 9216)  { bid -= 8960;  s = s2; d = d2; nt = 65536;  }
    else if (bid < 10240) { bid -= 9216;  s = s3; d = d3; nt = 262144; }
    else                  { bid -= 10240; s = s4; d = d4; nt = 262144; }
    int i = bid * 256 + threadIdx.x;
    if (i < nt) {
        float4 v = ((const float4*)s)[i];
        uint2 o;
        o.x = (uint32_t)f2bf(v.x) | ((uint32_t)f2bf(v.y) << 16);
        o.y = (uint32_t)f2bf(v.z) | ((uint32_t)f2bf(v.w) << 16);
        ((uint2*)d)[i] = o;
    }
}

// ---------------------------------------------------------------------------
// Conv chain kernel: levels 1..8 in ONE launch.
// Block = (n, h, q): q = quarter of the time range; downsampling is local
// (out row r needs in rows 2r,2r+1) so each quarter-chain is self-contained.
// Levels ping-pong in LDS (XOR chunk swizzle: chunk ^ (row&7) on 16B chunks).
// FIX vs round 5: WB is 8192 u16 (full 64x128 weights), staged as 4x256 chunks.
// ---------------------------------------------------------------------------
__global__ __launch_bounds__(256, 2)
void conv_chain_kernel(const u16* __restrict__ src_bf, u16* __restrict__ lvl_bf,
                       const u16* __restrict__ cw, const float* __restrict__ cb)
{
    __shared__ u16 BIG[16384];   // 32KB: L1 input (256 rows x 64ch), then even-level outs
    __shared__ u16 MID[8192];    // 16KB: odd-level outs
    __shared__ u16 WB[8192];     // 16KB: per-level weights [o][128]  (FIXED size)
    const int tid = threadIdx.x;
    const int l = tid & 63, w = tid >> 6;
    const int bid = blockIdx.x;          // n*32 + h*4 + q
    const int q  = bid & 3;
    const int h  = (bid >> 2) & 7;
    const int n  = bid >> 5;

    // stage L1 input: src rows n*1024 + q*256 + [0,256), cols h*64..+64
    {
        const u16* base = src_bf + ((size_t)n * 1024 + q * 256) * 512 + h * 64;
        #pragma unroll
        for (int j = 0; j < 8; j++) {
            int c = j * 256 + w * 64 + l;          // chunk index (16B units)
            int row = c >> 3, lch = c & 7;
            int gch = lch ^ (row & 7);
            gload16(base + (size_t)row * 512 + gch * 8,
                    BIG + (size_t)(j * 256 + w * 64) * 8);
        }
    }

    const u16* IN = BIG;
    u16* OUTb = MID;
    int R = 128;            // out rows per partition this level
    int T = 512;            // out rows per chain this level
    size_t rowOff = 0;      // lvl_bf row offset of this level's region
    for (int lvl = 1; lvl <= 8; lvl++) {
        // stage this level's weights (16KB = 1024 chunks) into WB
        {
            const u16* wsrc = cw + (size_t)(lvl - 1) * 8192;
            #pragma unroll
            for (int j = 0; j < 4; j++) {
                int c = j * 256 + w * 64 + l;      // 0..1023
                int o = c >> 4, lch = c & 15;
                int gch = lch ^ (o & 7);
                gload16(wsrc + o * 128 + gch * 8, WB + (size_t)(j * 256 + w * 64) * 8);
            }
        }
        asm volatile("s_waitcnt vmcnt(0)" ::: "memory");
        __syncthreads();

        const int nrt = (R + 15) >> 4;
        const int maxil = 2 * R - 1;
        for (int f = w; f < nrt * 4; f += 4) {
            int rt = f >> 2, nc = f & 3;
            int o = nc * 16 + (l & 15);
            f32x4 acc = {0.f, 0.f, 0.f, 0.f};
            #pragma unroll
            for (int s = 0; s < 4; s++) {
                int il = 2 * (rt * 16 + (l & 15)) + (s >> 1);
                if (il > maxil) il = maxil;
                int ach = (((s & 1) * 4) + (l >> 4)) ^ (il & 7);
                bf16x8 av = *(const bf16x8*)(IN + il * 64 + ach * 8);
                int bch = (s * 4 + (l >> 4)) ^ (o & 7);
                bf16x8 bv = *(const bf16x8*)(WB + o * 128 + bch * 8);
                acc = __builtin_amdgcn_mfma_f32_16x16x32_bf16(av, bv, acc, 0, 0, 0);
            }
            float bb = cb[(lvl - 1) * 64 + o];
            #pragma unroll
            for (int reg = 0; reg < 4; reg++) {
                int rloc = rt * 16 + (l >> 4) * 4 + reg;
                if (rloc < R) {
                    float v = fmaxf(acc[reg] + bb, 0.f);
                    u16 b16 = f2bf(v);
                    lvl_bf[(rowOff + (size_t)n * T + (size_t)q * R + rloc) * 512 + h * 64 + o] = b16;
                    OUTb[rloc * 64 + (((o >> 3) ^ (rloc & 7)) << 3) + (o & 7)] = b16;
                }
            }
        }
        __syncthreads();
        const u16* tmp = IN; IN = OUTb; OUTb = (u16*)tmp;
        rowOff += (size_t)16 * T;
        T >>= 1; R >>= 1;
    }
}

// ---------------------------------------------------------------------------
// Conv tail: levels 9 and 10 (tiny). Block per (n,h).
// ---------------------------------------------------------------------------
__global__ void conv_tail_kernel(u16* __restrict__ lvl_bf, const u16* __restrict__ cw,
                                 const float* __restrict__ cb)
{
    const int h = blockIdx.x & 7, n = blockIdx.x >> 3;
    const int tid = threadIdx.x;
    __shared__ float L8s[4][64];
    __shared__ float L9s[2][64];
    {
        int r = tid >> 6, c = tid & 63;   // 256 threads = 4 rows x 64 cols
        L8s[r][c] = bf2f(lvl_bf[((size_t)16256 + n * 4 + r) * 512 + h * 64 + c]);
    }
    __syncthreads();
    if (tid < 128) {
        int t = tid >> 6, o = tid & 63;
        const u16* wr = cw + (size_t)8 * 8192 + o * 128;
        float acc = cb[8 * 64 + o];
        #pragma unroll
        for (int k = 0; k < 2; k++)
            #pragma unroll 16
            for (int ci = 0; ci < 64; ci++)
                acc += L8s[2 * t + k][ci] * bf2f(wr[k * 64 + ci]);
        acc = fmaxf(acc, 0.f);
        L9s[t][o] = acc;
        lvl_bf[((size_t)16320 + n * 2 + t) * 512 + h * 64 + o] = f2bf(acc);
    }
    __syncthreads();
    if (tid < 64) {
        int o = tid;
        const u16* wr = cw + (size_t)9 * 8192 + o * 128;
        float acc = cb[9 * 64 + o];
        #pragma unroll
        for (int k = 0; k < 2; k++)
            #pragma unroll 16
            for (int ci = 0; ci < 64; ci++)
                acc += L9s[k][ci] * bf2f(wr[k * 64 + ci]);
        acc = fmaxf(acc, 0.f);
        lvl_bf[((size_t)16352 + n) * 512 + h * 64 + o] = f2bf(acc);
    }
}

// ---------------------------------------------------------------------------
// bf16 MFMA GEMM, 128x128 tile, BK=32:
//  + XCD-chunked bijective block swizzle (1-D grid)
//  + depth-3 prefetch: 4-buffer LDS ring, counted vmcnt(12) steady state
//  + vectorized epilogue via per-wave LDS transpose
// ---------------------------------------------------------------------------
__global__ __launch_bounds__(256, 2)
void mfma_gemm(const u16* __restrict__ A, const u16* __restrict__ W,
               const float* __restrict__ bias, const float* __restrict__ residual,
               float* __restrict__ Cf, u16* __restrict__ Cb,
               int M, int K, int N, int relu, int gx)
{
    __shared__ u16 lds[32768];   // 64 KB: 4 ring buffers x (A 8KB + B 8KB); epilogue reuse
    const int tid = threadIdx.x;
    const int l = tid & 63, w = tid >> 6;
    const int wm = w >> 1, wn = w & 1;

    const int nwg = gridDim.x;
    const int q = nwg >> 3, r = nwg & 7;
    const int xcd = blockIdx.x & 7, idx = blockIdx.x >> 3;
    const int lin = (xcd < r ? xcd * (q + 1) : r * (q + 1) + (xcd - r) * q) + idx;
    const int by = lin / gx, bx = lin - by * gx;
    const int rowBase = by * 128, colBase = bx * 128;

    f32x4 acc[4][4];
    #pragma unroll
    for (int m = 0; m < 4; m++)
        #pragma unroll
        for (int n = 0; n < 4; n++) acc[m][n] = 0.f;

    int rA0 = rowBase + w * 16 + (l >> 2);        if (rA0 > M - 1) rA0 = M - 1;
    int rA1 = rowBase + 64 + w * 16 + (l >> 2);   if (rA1 > M - 1) rA1 = M - 1;
    const u16* gA0 = A + (size_t)rA0 * K + (l & 3) * 8;
    const u16* gA1 = A + (size_t)rA1 * K + (l & 3) * 8;
    const u16* gB0 = W + (size_t)(colBase + w * 16 + (l >> 2)) * K + (l & 3) * 8;
    const u16* gB1 = W + (size_t)(colBase + 64 + w * 16 + (l >> 2)) * K + (l & 3) * 8;

    const int NT = K >> 5;
    auto STAGE = [&](int tt) {
        const int kb = tt << 5;
        u16* d = lds + (tt & 3) * 8192 + w * 512;   // wave-uniform dests
        gload16(gA0 + kb, d);
        gload16(gA1 + kb, d + 2048);
        gload16(gB0 + kb, d + 4096);
        gload16(gB1 + kb, d + 4096 + 2048);
    };
    STAGE(0);
    if (NT > 1) STAGE(1);
    if (NT > 2) STAGE(2);

    for (int t = 0; t < NT; ++t) {
        if (t + 3 < NT) STAGE(t + 3);
        const int rem = NT - 1 - t;
        if (rem >= 3)      asm volatile("s_waitcnt vmcnt(12)" ::: "memory");
        else if (rem == 2) asm volatile("s_waitcnt vmcnt(8)" ::: "memory");
        else if (rem == 1) asm volatile("s_waitcnt vmcnt(4)" ::: "memory");
        else               asm volatile("s_waitcnt vmcnt(0)" ::: "memory");
        __builtin_amdgcn_s_barrier();
        __builtin_amdgcn_sched_barrier(0);

        const u16* bufc = lds + (t & 3) * 8192;
        const u16* pa = bufc + (wm * 64 + (l & 15)) * 32 + (l >> 4) * 8;
        const u16* pb = bufc + 4096 + (wn * 64 + (l & 15)) * 32 + (l >> 4) * 8;
        bf16x8 av[4], bv[4];
        #pragma unroll
        for (int m = 0; m < 4; m++) av[m] = *(const bf16x8*)(pa + m * 512);
        #pragma unroll
        for (int n = 0; n < 4; n++) bv[n] = *(const bf16x8*)(pb + n * 512);
        #pragma unroll
        for (int m = 0; m < 4; m++)
            #pragma unroll
            for (int n = 0; n < 4; n++)
                acc[m][n] = __builtin_amdgcn_mfma_f32_16x16x32_bf16(av[m], bv[n], acc[m][n], 0, 0, 0);

        __builtin_amdgcn_sched_barrier(0);
        __builtin_amdgcn_s_barrier();   // all waves done reading bufc
        __builtin_amdgcn_sched_barrier(0);
    }

    // ---- epilogue: per-wave LDS transpose -> coalesced vector stores ----
    const int cc = colBase + wn * 64 + (l & 15);
    float bs4[4];
    #pragma unroll
    for (int n = 0; n < 4; n++) bs4[n] = bias[cc + n * 16];

    if (Cb) {
        u16* WS = lds + w * 2048;   // 4 KB/wave
        #pragma unroll
        for (int hh = 0; hh < 2; hh++) {
            #pragma unroll
            for (int mi = 0; mi < 2; mi++) {
                #pragma unroll
                for (int n = 0; n < 4; n++) {
                    int colv = n * 16 + (l & 15);
                    #pragma unroll
                    for (int reg = 0; reg < 4; reg++) {
                        int rowh = mi * 16 + (l >> 4) * 4 + reg;
                        float v = acc[hh * 2 + mi][n][reg] + bs4[n];
                        if (relu) v = fmaxf(v, 0.f);
                        WS[rowh * 64 + (colv ^ (((rowh >> 2) & 3) << 4))] = f2bf(v);
                    }
                }
            }
            asm volatile("s_waitcnt lgkmcnt(0)" ::: "memory");
            __builtin_amdgcn_sched_barrier(0);
            #pragma unroll
            for (int j = 0; j < 4; j++) {
                int rowh = (l >> 3) + 8 * j;
                int col8 = (l & 7) * 8;
                int colx = col8 ^ (((rowh >> 2) & 3) << 4);
                uint4 v = *(const uint4*)(WS + rowh * 64 + colx);
                int grow = rowBase + wm * 64 + hh * 32 + rowh;
                if (grow < M)
                    *(uint4*)(Cb + (size_t)grow * N + colBase + wn * 64 + col8) = v;
            }
        }
    } else {
        float* WSf = (float*)lds + w * 2048;   // 8 KB/wave
        #pragma unroll
        for (int hh = 0; hh < 2; hh++) {
            #pragma unroll
            for (int mi = 0; mi < 2; mi++) {
                #pragma unroll
                for (int n = 0; n < 4; n++) {
                    int colv = n * 16 + (l & 15);
                    #pragma unroll
                    for (int reg = 0; reg < 4; reg++) {
                        int rowh = mi * 16 + (l >> 4) * 4 + reg;
                        WSf[rowh * 64 + (colv ^ (((rowh >> 2) & 3) << 4))] =
                            acc[hh * 2 + mi][n][reg] + bs4[n];
                    }
                }
            }
            asm volatile("s_waitcnt lgkmcnt(0)" ::: "memory");
            __builtin_amdgcn_sched_barrier(0);
            #pragma unroll
            for (int j = 0; j < 8; j++) {
                int rowh = (l >> 4) + 4 * j;
                int col4 = (l & 15) * 4;
                int colx = col4 ^ (((rowh >> 2) & 3) << 4);
                float4 v = *(const float4*)(WSf + rowh * 64 + colx);
                int grow = rowBase + wm * 64 + hh * 32 + rowh;
                if (grow < M) {
                    int gcol = colBase + wn * 64 + col4;
                    if (residual) {
                        float4 rr = *(const float4*)&residual[(size_t)grow * N + gcol];
                        v.x += rr.x; v.y += rr.y; v.z += rr.z; v.w += rr.w;
                    }
                    if (relu) {
                        v.x = fmaxf(v.x, 0.f); v.y = fmaxf(v.y, 0.f);
                        v.z = fmaxf(v.z, 0.f); v.w = fmaxf(v.w, 0.f);
                    }
                    *(float4*)&Cf[(size_t)grow * N + gcol] = v;
                }
            }
        }
    }
}

// ---------------------------------------------------------------------------
// Attention (bf16 in/out), unchanged.
// ---------------------------------------------------------------------------
__global__ void attn_kernel(const u16* __restrict__ QKV, const u16* __restrict__ KVs,
                            u16* __restrict__ O)
{
    const int wv   = threadIdx.x >> 6;
    const int lane = threadIdx.x & 63;
    const int b    = blockIdx.x * 4 + wv;
    const int h    = lane >> 3;
    const int d8   = lane & 7;
    const int n = b >> 10, pos = b & 1023;

    float q[8];
    ld8bf(QKV + (size_t)b * 1536 + h * 64 + d8 * 8, q);

    float sc[NSCALES];
    {
        float kk[8];
        ld8bf(QKV + (size_t)b * 1536 + 512 + h * 64 + d8 * 8, kk);
        float p = 0.f;
        #pragma unroll
        for (int j = 0; j < 8; j++) p += q[j] * kk[j];
        p += __shfl_xor(p, 1); p += __shfl_xor(p, 2); p += __shfl_xor(p, 4);
        sc[0] = p * 0.125f;
    }
    {
        int rowOff = 0;
        #pragma unroll
        for (int s = 1; s <= NLEVELS; s++) {
            int Ls = 1024 >> s;
            int row = rowOff + n * Ls + (pos >> s);
            float kk[8];
            ld8bf(KVs + (size_t)row * 1024 + h * 64 + d8 * 8, kk);
            float p = 0.f;
            #pragma unroll
            for (int j = 0; j < 8; j++) p += q[j] * kk[j];
            p += __shfl_xor(p, 1); p += __shfl_xor(p, 2); p += __shfl_xor(p, 4);
            sc[s] = p * 0.125f;
            rowOff += 16 * Ls;
        }
    }
    float m = sc[0];
    #pragma unroll
    for (int s = 1; s < NSCALES; s++) m = fmaxf(m, sc[s]);
    float sum = 0.f;
    #pragma unroll
    for (int s = 0; s < NSCALES; s++) { sc[s] = __expf(sc[s] - m); sum += sc[s]; }
    float inv = 1.f / sum;

    float o[8] = {};
    {
        float vv[8];
        ld8bf(QKV + (size_t)b * 1536 + 1024 + h * 64 + d8 * 8, vv);
        float a = sc[0] * inv;
        #pragma unroll
        for (int j = 0; j < 8; j++) o[j] += a * vv[j];
    }
    {
        int rowOff = 0;
        #pragma unroll
        for (int s = 1; s <= NLEVELS; s++) {
            int Ls = 1024 >> s;
            int row = rowOff + n * Ls + (pos >> s);
            float vv[8];
            ld8bf(KVs + (size_t)row * 1024 + 512 + h * 64 + d8 * 8, vv);
            float a = sc[s] * inv;
            #pragma unroll
            for (int j = 0; j < 8; j++) o[j] += a * vv[j];
            rowOff += 16 * Ls;
        }
    }
    uint4 pk;
    pk.x = (uint32_t)f2bf(o[0]) | ((uint32_t)f2bf(o[1]) << 16);
    pk.y = (uint32_t)f2bf(o[2]) | ((uint32_t)f2bf(o[3]) << 16);
    pk.z = (uint32_t)f2bf(o[4]) | ((uint32_t)f2bf(o[5]) << 16);
    pk.w = (uint32_t)f2bf(o[6]) | ((uint32_t)f2bf(o[7]) << 16);
    *(uint4*)(O + (size_t)b * 512 + h * 64 + d8 * 8) = pk;
}

// ---------------------------------------------------------------------------
// LayerNorm over E=512; optional secondary bf16 output.
// ---------------------------------------------------------------------------
__global__ void ln_kernel(const float* __restrict__ in, float* __restrict__ out,
                          const float* __restrict__ w, const float* __restrict__ b,
                          u16* __restrict__ out_bf)
{
    const int row = blockIdx.x;
    const int tid = threadIdx.x;
    float2 v = *(const float2*)&in[(size_t)row * EE + tid * 2];
    float s  = v.x + v.y;
    float s2 = v.x * v.x + v.y * v.y;
    #pragma unroll
    for (int m = 1; m < 64; m <<= 1) { s += __shfl_xor(s, m); s2 += __shfl_xor(s2, m); }
    __shared__ float ss[4], ss2[4];
    int wv = tid >> 6;
    if ((tid & 63) == 0) { ss[wv] = s; ss2[wv] = s2; }
    __syncthreads();
    s  = ss[0] + ss[1] + ss[2] + ss[3];
    s2 = ss2[0] + ss2[1] + ss2[2] + ss2[3];
    float mu  = s * (1.f / 512.f);
    float var = s2 * (1.f / 512.f) - mu * mu;
    float rs  = rsqrtf(var + 1e-5f);
    float2 o;
    o.x = (v.x - mu) * rs * w[tid * 2]     + b[tid * 2];
    o.y = (v.y - mu) * rs * w[tid * 2 + 1] + b[tid * 2 + 1];
    *(float2*)&out[(size_t)row * EE + tid * 2] = o;
    if (out_bf) {
        uint32_t pk = (uint32_t)f2bf(o.x) | ((uint32_t)f2bf(o.y) << 16);
        *(uint32_t*)&out_bf[(size_t)row * EE + tid * 2] = pk;
    }
}

// ---------------------------------------------------------------------------
extern "C" void kernel_launch(void* const* d_in, const int* in_sizes, int n_in,
                              void* d_out, int out_size, void* d_ws, size_t ws_size,
                              hipStream_t stream)
{
    const float* src        = (const float*)d_in[0];
    const float* conv_w     = (const float*)d_in[1];
    const float* conv_b     = (const float*)d_in[2];
    const float* in_proj_w  = (const float*)d_in[3];
    const float* in_proj_b  = (const float*)d_in[4];
    const float* out_proj_w = (const float*)d_in[5];
    const float* out_proj_b = (const float*)d_in[6];
    const float* ln1_w      = (const float*)d_in[7];
    const float* ln1_b      = (const float*)d_in[8];
    const float* ln2_w      = (const float*)d_in[9];
    const float* ln2_b      = (const float*)d_in[10];
    const float* w1         = (const float*)d_in[11];
    const float* b1         = (const float*)d_in[12];
    const float* w2         = (const float*)d_in[13];
    const float* b2         = (const float*)d_in[14];

    char*  wsb    = (char*)d_ws;
    float* out    = (float*)d_out;
    u16*   src_bf = (u16*)(wsb + B_SRCBF);
    u16*   lvl_bf = (u16*)(wsb + B_LVLBF);
    u16*   QKV    = (u16*)(wsb + B_QKV);
    u16*   KVs    = (u16*)(wsb + B_KVS);
    u16*   O_bf   = (u16*)(wsb + B_OBF);
    float* X      = (float*)(wsb + B_X);
    u16*   X_bf   = (u16*)(wsb + B_XBF);
    u16*   inw_bf = (u16*)(wsb + B_WBF);
    u16*   outw_bf= inw_bf + 786432;
    u16*   w1_bf  = outw_bf + 262144;
    u16*   w2_bf  = w1_bf + 1048576;
    u16*   cw_bf  = w2_bf + 1048576;
    u16*   FFH    = (u16*)(wsb + B_FFH);

    // 0) cast src + weights to bf16 (+ conv_w repack)
    cast_all_kernel<<<11344, 256, 0, stream>>>(src, in_proj_w, out_proj_w, w1, w2, conv_w,
                                               src_bf, inw_bf, outw_bf, w1_bf, w2_bf, cw_bf);

    // 1) conv pyramid: levels 1..8 in one launch, 9..10 in a tiny tail
    conv_chain_kernel<<<NB * NHEADS * 4, 256, 0, stream>>>(src_bf, lvl_bf, cw_bf, conv_b);
    conv_tail_kernel<<<NB * NHEADS, 256, 0, stream>>>(lvl_bf, cw_bf, conv_b);

    // 2) QKV = src_bf @ in_proj_w^T + b  (16384 x 1536), gx=12
    mfma_gemm<<<12 * 128, 256, 0, stream>>>(
        src_bf, inw_bf, in_proj_b, nullptr, nullptr, QKV, BROWS, EE, 1536, 0, 12);

    // 3) KVs = lvl_bf @ Wkv^T + b_kv  (16368 x 1024), gx=8
    mfma_gemm<<<8 * 128, 256, 0, stream>>>(
        lvl_bf, inw_bf + (size_t)512 * 512, in_proj_b + 512, nullptr, nullptr, KVs,
        16368, EE, 1024, 0, 8);

    // 4) attention -> O_bf
    attn_kernel<<<BROWS / 4, 256, 0, stream>>>(QKV, KVs, O_bf);

    // 5) X = O_bf @ out_proj^T + b  (fp32), gx=4
    mfma_gemm<<<4 * 128, 256, 0, stream>>>(
        O_bf, outw_bf, out_proj_b, nullptr, X, nullptr, BROWS, EE, EE, 0, 4);

    // 6) LN1 in place (+ bf16 copy)
    ln_kernel<<<BROWS, 256, 0, stream>>>(X, X, ln1_w, ln1_b, X_bf);

    // 7) FFH = relu(X_bf @ w1^T + b1)  (bf16), gx=16
    mfma_gemm<<<16 * 128, 256, 0, stream>>>(
        X_bf, w1_bf, b1, nullptr, nullptr, FFH, BROWS, EE, DFF, 1, 16);

    // 8) out = FFH @ w2^T + b2 + X  (fp32), gx=4
    mfma_gemm<<<4 * 128, 256, 0, stream>>>(
        FFH, w2_bf, b2, X, out, nullptr, BROWS, DFF, EE, 0, 4);

    // 9) LN2 in place on out
    ln_kernel<<<BROWS, 256, 0, stream>>>(out, out, ln2_w, ln2_b, nullptr);
}

// Round 7
// 264.907 us; speedup vs baseline: 11.7175x; 1.0698x over previous
//
#include <hip/hip_runtime.h>
#include <hip/hip_bf16.h>
#include <stdint.h>
#include <math.h>

// Problem constants
#define NB      16
#define LL      1024
#define EE      512
#define NHEADS  8
#define DFF     2048
#define NLEVELS 10
#define NSCALES 11
#define BROWS   (NB * LL)       // 16384

typedef unsigned short u16;
typedef __attribute__((ext_vector_type(8))) short bf16x8;   // 8 bf16 = 4 VGPRs (MFMA A/B frag)
typedef __attribute__((ext_vector_type(4))) float f32x4;    // MFMA C/D frag

// ---------------- workspace layout (byte offsets) ----------------
static const size_t B_SRCBF = 0;                         // 16,777,216
static const size_t B_LVLBF = 16777216;                  // 16,760,832
static const size_t B_QKV   = 33538048;                  // 50,331,648
static const size_t B_KVS   = 83869696;                  // 33,521,664
static const size_t B_OBF   = 117391360;                 // 16,777,216
static const size_t B_X     = 134168576;                 // 33,554,432
static const size_t B_XBF   = 167723008;                 // 16,777,216
static const size_t B_WBF   = 184500224;                 // weights
static const size_t B_FFH   = 0;                         // overlaps dead-by-then buffers

// ---------------- helpers ----------------
__device__ __forceinline__ u16 f2bf(float x) {
    union { float f; uint32_t u; } c; c.f = x;
    uint32_t u = c.u + 0x7FFFu + ((c.u >> 16) & 1u);
    return (u16)(u >> 16);
}
__device__ __forceinline__ float bf2f(u16 v) {
    union { uint32_t u; float f; } c; c.u = ((uint32_t)v) << 16; return c.f;
}
__device__ __forceinline__ void ld8bf(const u16* p, float* f) {
    uint4 r = *(const uint4*)p;
    uint32_t ws[4] = { r.x, r.y, r.z, r.w };
    #pragma unroll
    for (int j = 0; j < 4; j++) {
        union { uint32_t u; float g; } lo, hi;
        lo.u = ws[j] << 16; hi.u = ws[j] & 0xFFFF0000u;
        f[2 * j] = lo.g; f[2 * j + 1] = hi.g;
    }
}
__device__ __forceinline__ void gload16(const u16* g, u16* l) {
    __builtin_amdgcn_global_load_lds(
        (const __attribute__((address_space(1))) void*)g,
        (__attribute__((address_space(3))) void*)l, 16, 0, 0);
}

// ---------------------------------------------------------------------------
// Fused cast kernel: src + 4 weight tensors -> bf16, plus conv_w repack:
// wr[lvl][o][k*64+ci] = conv_w[lvl][o][ci][k].
// ---------------------------------------------------------------------------
__global__ void cast_all_kernel(const float* __restrict__ s0, const float* __restrict__ s1,
                                const float* __restrict__ s2, const float* __restrict__ s3,
                                const float* __restrict__ s4, const float* __restrict__ cw,
                                u16* __restrict__ d0, u16* __restrict__ d1,
                                u16* __restrict__ d2, u16* __restrict__ d3,
                                u16* __restrict__ d4, u16* __restrict__ dw)
{
    int bid = blockIdx.x;
    if (bid >= 11264) {   // conv_w repack: 81920 outputs
        int base = (bid - 11264) * 1024 + threadIdx.x * 4;
        #pragma unroll
        for (int j = 0; j < 4; j++) {
            int idx = base + j;
            int lvl = idx >> 13, rem = idx & 8191;
            int o = rem >> 7, ck = rem & 127;
            int k = ck >> 6, ci = ck & 63;
            dw[idx] = f2bf(cw[(lvl << 13) + (o << 7) + (ci << 1) + k]);
        }
        return;
    }
    const float* s; u16* d; int nt;
    if      (bid < 8192)  { s = s0; d = d0; nt = 2097152; }
    else if (bid < 8960)  { bid -= 8192;  s = s1; d = d1; nt = 196608; }
    else if (bid < 9216)  { bid -= 8960;  s = s2; d = d2; nt = 65536;  }
    else if (bid < 10240) { bid -= 9216;  s = s3; d = d3; nt = 262144; }
    else                  { bid -= 10240; s = s4; d = d4; nt = 262144; }
    int i = bid * 256 + threadIdx.x;
    if (i < nt) {
        float4 v = ((const float4*)s)[i];
        uint2 o;
        o.x = (uint32_t)f2bf(v.x) | ((uint32_t)f2bf(v.y) << 16);
        o.y = (uint32_t)f2bf(v.z) | ((uint32_t)f2bf(v.w) << 16);
        ((uint2*)d)[i] = o;
    }
}

// ---------------------------------------------------------------------------
// Conv chain kernel: levels 1..8 in ONE launch (unchanged from round 6).
// ---------------------------------------------------------------------------
__global__ __launch_bounds__(256, 2)
void conv_chain_kernel(const u16* __restrict__ src_bf, u16* __restrict__ lvl_bf,
                       const u16* __restrict__ cw, const float* __restrict__ cb)
{
    __shared__ u16 BIG[16384];   // 32KB
    __shared__ u16 MID[8192];    // 16KB
    __shared__ u16 WB[8192];     // 16KB: per-level weights [o][128]
    const int tid = threadIdx.x;
    const int l = tid & 63, w = tid >> 6;
    const int bid = blockIdx.x;          // n*32 + h*4 + q
    const int q  = bid & 3;
    const int h  = (bid >> 2) & 7;
    const int n  = bid >> 5;

    {
        const u16* base = src_bf + ((size_t)n * 1024 + q * 256) * 512 + h * 64;
        #pragma unroll
        for (int j = 0; j < 8; j++) {
            int c = j * 256 + w * 64 + l;
            int row = c >> 3, lch = c & 7;
            int gch = lch ^ (row & 7);
            gload16(base + (size_t)row * 512 + gch * 8,
                    BIG + (size_t)(j * 256 + w * 64) * 8);
        }
    }

    const u16* IN = BIG;
    u16* OUTb = MID;
    int R = 128;
    int T = 512;
    size_t rowOff = 0;
    for (int lvl = 1; lvl <= 8; lvl++) {
        {
            const u16* wsrc = cw + (size_t)(lvl - 1) * 8192;
            #pragma unroll
            for (int j = 0; j < 4; j++) {
                int c = j * 256 + w * 64 + l;
                int o = c >> 4, lch = c & 15;
                int gch = lch ^ (o & 7);
                gload16(wsrc + o * 128 + gch * 8, WB + (size_t)(j * 256 + w * 64) * 8);
            }
        }
        asm volatile("s_waitcnt vmcnt(0)" ::: "memory");
        __syncthreads();

        const int nrt = (R + 15) >> 4;
        const int maxil = 2 * R - 1;
        for (int f = w; f < nrt * 4; f += 4) {
            int rt = f >> 2, nc = f & 3;
            int o = nc * 16 + (l & 15);
            f32x4 acc = {0.f, 0.f, 0.f, 0.f};
            #pragma unroll
            for (int s = 0; s < 4; s++) {
                int il = 2 * (rt * 16 + (l & 15)) + (s >> 1);
                if (il > maxil) il = maxil;
                int ach = (((s & 1) * 4) + (l >> 4)) ^ (il & 7);
                bf16x8 av = *(const bf16x8*)(IN + il * 64 + ach * 8);
                int bch = (s * 4 + (l >> 4)) ^ (o & 7);
                bf16x8 bv = *(const bf16x8*)(WB + o * 128 + bch * 8);
                acc = __builtin_amdgcn_mfma_f32_16x16x32_bf16(av, bv, acc, 0, 0, 0);
            }
            float bb = cb[(lvl - 1) * 64 + o];
            #pragma unroll
            for (int reg = 0; reg < 4; reg++) {
                int rloc = rt * 16 + (l >> 4) * 4 + reg;
                if (rloc < R) {
                    float v = fmaxf(acc[reg] + bb, 0.f);
                    u16 b16 = f2bf(v);
                    lvl_bf[(rowOff + (size_t)n * T + (size_t)q * R + rloc) * 512 + h * 64 + o] = b16;
                    OUTb[rloc * 64 + (((o >> 3) ^ (rloc & 7)) << 3) + (o & 7)] = b16;
                }
            }
        }
        __syncthreads();
        const u16* tmp = IN; IN = OUTb; OUTb = (u16*)tmp;
        rowOff += (size_t)16 * T;
        T >>= 1; R >>= 1;
    }
}

// ---------------------------------------------------------------------------
// Conv tail: levels 9 and 10 (tiny). Block per (n,h).
// ---------------------------------------------------------------------------
__global__ void conv_tail_kernel(u16* __restrict__ lvl_bf, const u16* __restrict__ cw,
                                 const float* __restrict__ cb)
{
    const int h = blockIdx.x & 7, n = blockIdx.x >> 3;
    const int tid = threadIdx.x;
    __shared__ float L8s[4][64];
    __shared__ float L9s[2][64];
    {
        int r = tid >> 6, c = tid & 63;
        L8s[r][c] = bf2f(lvl_bf[((size_t)16256 + n * 4 + r) * 512 + h * 64 + c]);
    }
    __syncthreads();
    if (tid < 128) {
        int t = tid >> 6, o = tid & 63;
        const u16* wr = cw + (size_t)8 * 8192 + o * 128;
        float acc = cb[8 * 64 + o];
        #pragma unroll
        for (int k = 0; k < 2; k++)
            #pragma unroll 16
            for (int ci = 0; ci < 64; ci++)
                acc += L8s[2 * t + k][ci] * bf2f(wr[k * 64 + ci]);
        acc = fmaxf(acc, 0.f);
        L9s[t][o] = acc;
        lvl_bf[((size_t)16320 + n * 2 + t) * 512 + h * 64 + o] = f2bf(acc);
    }
    __syncthreads();
    if (tid < 64) {
        int o = tid;
        const u16* wr = cw + (size_t)9 * 8192 + o * 128;
        float acc = cb[9 * 64 + o];
        #pragma unroll
        for (int k = 0; k < 2; k++)
            #pragma unroll 16
            for (int ci = 0; ci < 64; ci++)
                acc += L9s[k][ci] * bf2f(wr[k * 64 + ci]);
        acc = fmaxf(acc, 0.f);
        lvl_bf[((size_t)16352 + n) * 512 + h * 64 + o] = f2bf(acc);
    }
}

// ---------------------------------------------------------------------------
// bf16 MFMA GEMM, 128x128 tile, BK=32:
//  + XCD-chunked bijective block swizzle (1-D grid)
//  + 3-buffer LDS ring (48KB), depth-2 prefetch, counted vmcnt(8) steady
//  + __launch_bounds__(256,3): 3 blocks/CU (round-6 lesson: occupancy > depth)
//  + vectorized epilogue via per-wave LDS transpose; optional bf16 residual
// ---------------------------------------------------------------------------
__global__ __launch_bounds__(256, 3)
void mfma_gemm(const u16* __restrict__ A, const u16* __restrict__ W,
               const float* __restrict__ bias, const float* __restrict__ residual,
               const u16* __restrict__ resb,
               float* __restrict__ Cf, u16* __restrict__ Cb,
               int M, int K, int N, int relu, int gx)
{
    __shared__ u16 lds[24576];   // 48 KB: 3 ring buffers x (A 8KB + B 8KB); epilogue reuse
    const int tid = threadIdx.x;
    const int l = tid & 63, w = tid >> 6;
    const int wm = w >> 1, wn = w & 1;

    const int nwg = gridDim.x;
    const int q = nwg >> 3, r = nwg & 7;
    const int xcd = blockIdx.x & 7, idx = blockIdx.x >> 3;
    const int lin = (xcd < r ? xcd * (q + 1) : r * (q + 1) + (xcd - r) * q) + idx;
    const int by = lin / gx, bx = lin - by * gx;
    const int rowBase = by * 128, colBase = bx * 128;

    f32x4 acc[4][4];
    #pragma unroll
    for (int m = 0; m < 4; m++)
        #pragma unroll
        for (int n = 0; n < 4; n++) acc[m][n] = 0.f;

    int rA0 = rowBase + w * 16 + (l >> 2);        if (rA0 > M - 1) rA0 = M - 1;
    int rA1 = rowBase + 64 + w * 16 + (l >> 2);   if (rA1 > M - 1) rA1 = M - 1;
    const u16* gA0 = A + (size_t)rA0 * K + (l & 3) * 8;
    const u16* gA1 = A + (size_t)rA1 * K + (l & 3) * 8;
    const u16* gB0 = W + (size_t)(colBase + w * 16 + (l >> 2)) * K + (l & 3) * 8;
    const u16* gB1 = W + (size_t)(colBase + 64 + w * 16 + (l >> 2)) * K + (l & 3) * 8;

    const int NT = K >> 5;
    auto STAGE = [&](int tt, int buf) {
        const int kb = tt << 5;
        u16* d = lds + buf * 8192 + w * 512;   // wave-uniform dests
        gload16(gA0 + kb, d);
        gload16(gA1 + kb, d + 2048);
        gload16(gB0 + kb, d + 4096);
        gload16(gB1 + kb, d + 4096 + 2048);
    };
    STAGE(0, 0);
    if (NT > 1) STAGE(1, 1);

    int cbuf = 0;   // compute buffer for iter t
    int sbuf = 2;   // stage buffer for tile t+2
    for (int t = 0; t < NT; ++t) {
        if (t + 2 < NT) STAGE(t + 2, sbuf);
        const int rem = NT - 1 - t;
        if (rem >= 2)      asm volatile("s_waitcnt vmcnt(8)" ::: "memory");
        else if (rem == 1) asm volatile("s_waitcnt vmcnt(4)" ::: "memory");
        else               asm volatile("s_waitcnt vmcnt(0)" ::: "memory");
        __builtin_amdgcn_s_barrier();
        __builtin_amdgcn_sched_barrier(0);

        const u16* bufc = lds + cbuf * 8192;
        const u16* pa = bufc + (wm * 64 + (l & 15)) * 32 + (l >> 4) * 8;
        const u16* pb = bufc + 4096 + (wn * 64 + (l & 15)) * 32 + (l >> 4) * 8;
        bf16x8 av[4], bv[4];
        #pragma unroll
        for (int m = 0; m < 4; m++) av[m] = *(const bf16x8*)(pa + m * 512);
        #pragma unroll
        for (int n = 0; n < 4; n++) bv[n] = *(const bf16x8*)(pb + n * 512);
        #pragma unroll
        for (int m = 0; m < 4; m++)
            #pragma unroll
            for (int n = 0; n < 4; n++)
                acc[m][n] = __builtin_amdgcn_mfma_f32_16x16x32_bf16(av[m], bv[n], acc[m][n], 0, 0, 0);

        __builtin_amdgcn_sched_barrier(0);
        __builtin_amdgcn_s_barrier();   // all waves done reading bufc
        __builtin_amdgcn_sched_barrier(0);

        cbuf = (cbuf == 2) ? 0 : cbuf + 1;
        sbuf = (sbuf == 2) ? 0 : sbuf + 1;
    }

    // ---- epilogue: per-wave LDS transpose -> coalesced vector stores ----
    const int cc = colBase + wn * 64 + (l & 15);
    float bs4[4];
    #pragma unroll
    for (int n = 0; n < 4; n++) bs4[n] = bias[cc + n * 16];

    if (Cb) {
        u16* WS = lds + w * 2048;   // 4 KB/wave
        #pragma unroll
        for (int hh = 0; hh < 2; hh++) {
            #pragma unroll
            for (int mi = 0; mi < 2; mi++) {
                #pragma unroll
                for (int n = 0; n < 4; n++) {
                    int colv = n * 16 + (l & 15);
                    #pragma unroll
                    for (int reg = 0; reg < 4; reg++) {
                        int rowh = mi * 16 + (l >> 4) * 4 + reg;
                        float v = acc[hh * 2 + mi][n][reg] + bs4[n];
                        if (relu) v = fmaxf(v, 0.f);
                        WS[rowh * 64 + (colv ^ (((rowh >> 2) & 3) << 4))] = f2bf(v);
                    }
                }
            }
            asm volatile("s_waitcnt lgkmcnt(0)" ::: "memory");
            __builtin_amdgcn_sched_barrier(0);
            #pragma unroll
            for (int j = 0; j < 4; j++) {
                int rowh = (l >> 3) + 8 * j;
                int col8 = (l & 7) * 8;
                int colx = col8 ^ (((rowh >> 2) & 3) << 4);
                uint4 v = *(const uint4*)(WS + rowh * 64 + colx);
                int grow = rowBase + wm * 64 + hh * 32 + rowh;
                if (grow < M)
                    *(uint4*)(Cb + (size_t)grow * N + colBase + wn * 64 + col8) = v;
            }
        }
    } else {
        float* WSf = (float*)lds + w * 2048;   // 8 KB/wave
        #pragma unroll
        for (int hh = 0; hh < 2; hh++) {
            #pragma unroll
            for (int mi = 0; mi < 2; mi++) {
                #pragma unroll
                for (int n = 0; n < 4; n++) {
                    int colv = n * 16 + (l & 15);
                    #pragma unroll
                    for (int reg = 0; reg < 4; reg++) {
                        int rowh = mi * 16 + (l >> 4) * 4 + reg;
                        WSf[rowh * 64 + (colv ^ (((rowh >> 2) & 3) << 4))] =
                            acc[hh * 2 + mi][n][reg] + bs4[n];
                    }
                }
            }
            asm volatile("s_waitcnt lgkmcnt(0)" ::: "memory");
            __builtin_amdgcn_sched_barrier(0);
            #pragma unroll
            for (int j = 0; j < 8; j++) {
                int rowh = (l >> 4) + 4 * j;
                int col4 = (l & 15) * 4;
                int colx = col4 ^ (((rowh >> 2) & 3) << 4);
                float4 v = *(const float4*)(WSf + rowh * 64 + colx);
                int grow = rowBase + wm * 64 + hh * 32 + rowh;
                if (grow < M) {
                    int gcol = colBase + wn * 64 + col4;
                    if (residual) {
                        float4 rr = *(const float4*)&residual[(size_t)grow * N + gcol];
                        v.x += rr.x; v.y += rr.y; v.z += rr.z; v.w += rr.w;
                    }
                    if (resb) {
                        uint2 rb = *(const uint2*)&resb[(size_t)grow * N + gcol];
                        v.x += bf2f((u16)(rb.x & 0xFFFF));
                        v.y += bf2f((u16)(rb.x >> 16));
                        v.z += bf2f((u16)(rb.y & 0xFFFF));
                        v.w += bf2f((u16)(rb.y >> 16));
                    }
                    if (relu) {
                        v.x = fmaxf(v.x, 0.f); v.y = fmaxf(v.y, 0.f);
                        v.z = fmaxf(v.z, 0.f); v.w = fmaxf(v.w, 0.f);
                    }
                    *(float4*)&Cf[(size_t)grow * N + gcol] = v;
                }
            }
        }
    }
}

// ---------------------------------------------------------------------------
// Attention (bf16 in/out), unchanged.
// ---------------------------------------------------------------------------
__global__ void attn_kernel(const u16* __restrict__ QKV, const u16* __restrict__ KVs,
                            u16* __restrict__ O)
{
    const int wv   = threadIdx.x >> 6;
    const int lane = threadIdx.x & 63;
    const int b    = blockIdx.x * 4 + wv;
    const int h    = lane >> 3;
    const int d8   = lane & 7;
    const int n = b >> 10, pos = b & 1023;

    float q[8];
    ld8bf(QKV + (size_t)b * 1536 + h * 64 + d8 * 8, q);

    float sc[NSCALES];
    {
        float kk[8];
        ld8bf(QKV + (size_t)b * 1536 + 512 + h * 64 + d8 * 8, kk);
        float p = 0.f;
        #pragma unroll
        for (int j = 0; j < 8; j++) p += q[j] * kk[j];
        p += __shfl_xor(p, 1); p += __shfl_xor(p, 2); p += __shfl_xor(p, 4);
        sc[0] = p * 0.125f;
    }
    {
        int rowOff = 0;
        #pragma unroll
        for (int s = 1; s <= NLEVELS; s++) {
            int Ls = 1024 >> s;
            int row = rowOff + n * Ls + (pos >> s);
            float kk[8];
            ld8bf(KVs + (size_t)row * 1024 + h * 64 + d8 * 8, kk);
            float p = 0.f;
            #pragma unroll
            for (int j = 0; j < 8; j++) p += q[j] * kk[j];
            p += __shfl_xor(p, 1); p += __shfl_xor(p, 2); p += __shfl_xor(p, 4);
            sc[s] = p * 0.125f;
            rowOff += 16 * Ls;
        }
    }
    float m = sc[0];
    #pragma unroll
    for (int s = 1; s < NSCALES; s++) m = fmaxf(m, sc[s]);
    float sum = 0.f;
    #pragma unroll
    for (int s = 0; s < NSCALES; s++) { sc[s] = __expf(sc[s] - m); sum += sc[s]; }
    float inv = 1.f / sum;

    float o[8] = {};
    {
        float vv[8];
        ld8bf(QKV + (size_t)b * 1536 + 1024 + h * 64 + d8 * 8, vv);
        float a = sc[0] * inv;
        #pragma unroll
        for (int j = 0; j < 8; j++) o[j] += a * vv[j];
    }
    {
        int rowOff = 0;
        #pragma unroll
        for (int s = 1; s <= NLEVELS; s++) {
            int Ls = 1024 >> s;
            int row = rowOff + n * Ls + (pos >> s);
            float vv[8];
            ld8bf(KVs + (size_t)row * 1024 + 512 + h * 64 + d8 * 8, vv);
            float a = sc[s] * inv;
            #pragma unroll
            for (int j = 0; j < 8; j++) o[j] += a * vv[j];
            rowOff += 16 * Ls;
        }
    }
    uint4 pk;
    pk.x = (uint32_t)f2bf(o[0]) | ((uint32_t)f2bf(o[1]) << 16);
    pk.y = (uint32_t)f2bf(o[2]) | ((uint32_t)f2bf(o[3]) << 16);
    pk.z = (uint32_t)f2bf(o[4]) | ((uint32_t)f2bf(o[5]) << 16);
    pk.w = (uint32_t)f2bf(o[6]) | ((uint32_t)f2bf(o[7]) << 16);
    *(uint4*)(O + (size_t)b * 512 + h * 64 + d8 * 8) = pk;
}

// ---------------------------------------------------------------------------
// LayerNorm over E=512: ONE WAVE PER ROW (4 rows/block), pure shuffle reduce.
// ---------------------------------------------------------------------------
__global__ void ln_kernel(const float* __restrict__ in, float* __restrict__ out,
                          const float* __restrict__ w, const float* __restrict__ b,
                          u16* __restrict__ out_bf)
{
    const int l = threadIdx.x & 63;
    const int row = blockIdx.x * 4 + (threadIdx.x >> 6);
    const float* p = in + (size_t)row * EE + l * 8;
    float4 v0 = *(const float4*)p;
    float4 v1 = *(const float4*)(p + 4);
    float s  = v0.x + v0.y + v0.z + v0.w + v1.x + v1.y + v1.z + v1.w;
    float s2 = v0.x * v0.x + v0.y * v0.y + v0.z * v0.z + v0.w * v0.w
             + v1.x * v1.x + v1.y * v1.y + v1.z * v1.z + v1.w * v1.w;
    #pragma unroll
    for (int m = 1; m < 64; m <<= 1) { s += __shfl_xor(s, m); s2 += __shfl_xor(s2, m); }
    float mu  = s * (1.f / 512.f);
    float var = s2 * (1.f / 512.f) - mu * mu;
    float rs  = rsqrtf(var + 1e-5f);
    float4 w0 = *(const float4*)&w[l * 8], w1 = *(const float4*)&w[l * 8 + 4];
    float4 b0 = *(const float4*)&b[l * 8], b1 = *(const float4*)&b[l * 8 + 4];
    float o[8];
    o[0] = (v0.x - mu) * rs * w0.x + b0.x;
    o[1] = (v0.y - mu) * rs * w0.y + b0.y;
    o[2] = (v0.z - mu) * rs * w0.z + b0.z;
    o[3] = (v0.w - mu) * rs * w0.w + b0.w;
    o[4] = (v1.x - mu) * rs * w1.x + b1.x;
    o[5] = (v1.y - mu) * rs * w1.y + b1.y;
    o[6] = (v1.z - mu) * rs * w1.z + b1.z;
    o[7] = (v1.w - mu) * rs * w1.w + b1.w;
    float* po = out + (size_t)row * EE + l * 8;
    *(float4*)po       = make_float4(o[0], o[1], o[2], o[3]);
    *(float4*)(po + 4) = make_float4(o[4], o[5], o[6], o[7]);
    if (out_bf) {
        uint4 pk;
        pk.x = (uint32_t)f2bf(o[0]) | ((uint32_t)f2bf(o[1]) << 16);
        pk.y = (uint32_t)f2bf(o[2]) | ((uint32_t)f2bf(o[3]) << 16);
        pk.z = (uint32_t)f2bf(o[4]) | ((uint32_t)f2bf(o[5]) << 16);
        pk.w = (uint32_t)f2bf(o[6]) | ((uint32_t)f2bf(o[7]) << 16);
        *(uint4*)(out_bf + (size_t)row * EE + l * 8) = pk;
    }
}

// ---------------------------------------------------------------------------
extern "C" void kernel_launch(void* const* d_in, const int* in_sizes, int n_in,
                              void* d_out, int out_size, void* d_ws, size_t ws_size,
                              hipStream_t stream)
{
    const float* src        = (const float*)d_in[0];
    const float* conv_w     = (const float*)d_in[1];
    const float* conv_b     = (const float*)d_in[2];
    const float* in_proj_w  = (const float*)d_in[3];
    const float* in_proj_b  = (const float*)d_in[4];
    const float* out_proj_w = (const float*)d_in[5];
    const float* out_proj_b = (const float*)d_in[6];
    const float* ln1_w      = (const float*)d_in[7];
    const float* ln1_b      = (const float*)d_in[8];
    const float* ln2_w      = (const float*)d_in[9];
    const float* ln2_b      = (const float*)d_in[10];
    const float* w1         = (const float*)d_in[11];
    const float* b1         = (const float*)d_in[12];
    const float* w2         = (const float*)d_in[13];
    const float* b2         = (const float*)d_in[14];

    char*  wsb    = (char*)d_ws;
    float* out    = (float*)d_out;
    u16*   src_bf = (u16*)(wsb + B_SRCBF);
    u16*   lvl_bf = (u16*)(wsb + B_LVLBF);
    u16*   QKV    = (u16*)(wsb + B_QKV);
    u16*   KVs    = (u16*)(wsb + B_KVS);
    u16*   O_bf   = (u16*)(wsb + B_OBF);
    float* X      = (float*)(wsb + B_X);
    u16*   X_bf   = (u16*)(wsb + B_XBF);
    u16*   inw_bf = (u16*)(wsb + B_WBF);
    u16*   outw_bf= inw_bf + 786432;
    u16*   w1_bf  = outw_bf + 262144;
    u16*   w2_bf  = w1_bf + 1048576;
    u16*   cw_bf  = w2_bf + 1048576;
    u16*   FFH    = (u16*)(wsb + B_FFH);

    // 0) cast src + weights to bf16 (+ conv_w repack)
    cast_all_kernel<<<11344, 256, 0, stream>>>(src, in_proj_w, out_proj_w, w1, w2, conv_w,
                                               src_bf, inw_bf, outw_bf, w1_bf, w2_bf, cw_bf);

    // 1) conv pyramid: levels 1..8 in one launch, 9..10 in a tiny tail
    conv_chain_kernel<<<NB * NHEADS * 4, 256, 0, stream>>>(src_bf, lvl_bf, cw_bf, conv_b);
    conv_tail_kernel<<<NB * NHEADS, 256, 0, stream>>>(lvl_bf, cw_bf, conv_b);

    // 2) QKV = src_bf @ in_proj_w^T + b  (16384 x 1536), gx=12
    mfma_gemm<<<12 * 128, 256, 0, stream>>>(
        src_bf, inw_bf, in_proj_b, nullptr, nullptr, nullptr, QKV, BROWS, EE, 1536, 0, 12);

    // 3) KVs = lvl_bf @ Wkv^T + b_kv  (16368 x 1024), gx=8
    mfma_gemm<<<8 * 128, 256, 0, stream>>>(
        lvl_bf, inw_bf + (size_t)512 * 512, in_proj_b + 512, nullptr, nullptr, nullptr, KVs,
        16368, EE, 1024, 0, 8);

    // 4) attention -> O_bf
    attn_kernel<<<BROWS / 4, 256, 0, stream>>>(QKV, KVs, O_bf);

    // 5) X = O_bf @ out_proj^T + b  (fp32), gx=4
    mfma_gemm<<<4 * 128, 256, 0, stream>>>(
        O_bf, outw_bf, out_proj_b, nullptr, nullptr, X, nullptr, BROWS, EE, EE, 0, 4);

    // 6) LN1 in place (+ bf16 copy)
    ln_kernel<<<BROWS / 4, 256, 0, stream>>>(X, X, ln1_w, ln1_b, X_bf);

    // 7) FFH = relu(X_bf @ w1^T + b1)  (bf16), gx=16
    mfma_gemm<<<16 * 128, 256, 0, stream>>>(
        X_bf, w1_bf, b1, nullptr, nullptr, nullptr, FFH, BROWS, EE, DFF, 1, 16);

    // 8) out = FFH @ w2^T + b2 + X_bf  (fp32 out, bf16 residual), gx=4
    mfma_gemm<<<4 * 128, 256, 0, stream>>>(
        FFH, w2_bf, b2, nullptr, X_bf, out, nullptr, BROWS, DFF, EE, 0, 4);

    // 9) LN2 in place on out
    ln_kernel<<<BROWS / 4, 256, 0, stream>>>(out, out, ln2_w, ln2_b, nullptr);
}